// Round 1
// baseline (214.252 us; speedup 1.0000x reference)
//
#include <hip/hip_runtime.h>
#include <math.h>

// ---------------------------------------------------------------------------
// GCN 2-layer forward on MI355X.
// Round 13: fuse gather-0 (layer-1 aggregation) with gemm2 into one kernel.
// Each block gathers 32 node rows (4 waves x 8 nodes, quarter-wave layout)
// into LDS [32][136] bf16 (pad -> 2-way bank conflict = free), then the 4
// waves run a 32x128 @ 128x128 MFMA GEMM (each wave a 32-col slice) writing
// h2 directly. Eliminates the g1 12.8 MB round-trip + one launch boundary.
// packed (hist) now aliases h2 (dead until k_ag2). Everything else = R12.
// ---------------------------------------------------------------------------

typedef unsigned int uint32;
typedef unsigned long long u64;
typedef __attribute__((ext_vector_type(8))) short bf16x8;   // 8 bf16 (4 VGPRs)
typedef __attribute__((ext_vector_type(4))) float f32x4;
typedef __attribute__((ext_vector_type(2))) float f32x2;

__device__ __forceinline__ unsigned short f2bf(float f) {   // RNE fp32->bf16
    uint32 b = __float_as_uint(f);
    return (unsigned short)((b + 0x7FFFu + ((b >> 16) & 1u)) >> 16);
}

__device__ __forceinline__ float2 bf2_decode(uint32 u) {
    return make_float2(__uint_as_float(u << 16),
                       __uint_as_float(u & 0xFFFF0000u));
}

// ---------------------------------------------------------------------------
// MFMA GEMM body: H[n x 128] = A[n x 128] @ W (WT bf16 transposed).
// 256 threads = 4 waves; each wave 32 rows x 128 cols (2x8 16x16 tiles),
// K=128 in 4 steps. AFP32: A fp32 (converted inline) vs bf16.
// OUTFP8: D written as fp8 e4m3 bytes vs bf16.
// ---------------------------------------------------------------------------
template <int AFP32, int OUTFP8>
__device__ __forceinline__ void gemm_body(const void* __restrict__ Ap,
                                          const unsigned short* __restrict__ WT,
                                          void* __restrict__ H,
                                          int n, int tb) {
    const int lane = threadIdx.x & 63;
    const int wv   = threadIdx.x >> 6;
    const int quad = lane >> 4;
    const int l16  = lane & 15;
    const int m0   = tb * 128 + wv * 32;
    f32x4 acc[2][8] = {};

    #pragma unroll
    for (int ks = 0; ks < 4; ++ks) {
        const int k0 = ks * 32 + quad * 8;
        bf16x8 a[2];
        #pragma unroll
        for (int rt = 0; rt < 2; ++rt) {
            int row = m0 + rt * 16 + l16;
            if (row >= n) row = n - 1;  // clamp; stores are guarded
            if (AFP32) {
                const float* Af = (const float*)Ap + (size_t)row * 128 + k0;
                float4 f0 = *(const float4*)(Af);
                float4 f1 = *(const float4*)(Af + 4);
                bf16x8 v;
                v[0] = (short)f2bf(f0.x); v[1] = (short)f2bf(f0.y);
                v[2] = (short)f2bf(f0.z); v[3] = (short)f2bf(f0.w);
                v[4] = (short)f2bf(f1.x); v[5] = (short)f2bf(f1.y);
                v[6] = (short)f2bf(f1.z); v[7] = (short)f2bf(f1.w);
                a[rt] = v;
            } else {
                const unsigned short* Ab = (const unsigned short*)Ap + (size_t)row * 128 + k0;
                a[rt] = *(const bf16x8*)Ab;
            }
        }
        #pragma unroll
        for (int ct = 0; ct < 8; ++ct) {
            bf16x8 b = *(const bf16x8*)(WT + (size_t)(ct * 16 + l16) * 128 + k0);
            acc[0][ct] = __builtin_amdgcn_mfma_f32_16x16x32_bf16(a[0], b, acc[0][ct], 0, 0, 0);
            acc[1][ct] = __builtin_amdgcn_mfma_f32_16x16x32_bf16(a[1], b, acc[1][ct], 0, 0, 0);
        }
    }

    // D layout: col = lane&15, row = quad*4 + reg  (m89-verified)
    #pragma unroll
    for (int rt = 0; rt < 2; ++rt) {
        #pragma unroll
        for (int r = 0; r < 4; ++r) {
            int row = m0 + rt * 16 + quad * 4 + r;
            if (row < n) {
                if (OUTFP8) {
                    unsigned char* o = (unsigned char*)H + (size_t)row * 128 + l16;
                    #pragma unroll
                    for (int cp = 0; cp < 4; ++cp) {
                        int pk = __builtin_amdgcn_cvt_pk_fp8_f32(
                            acc[rt][2 * cp][r], acc[rt][2 * cp + 1][r], 0, false);
                        o[(2 * cp) * 16]     = (unsigned char)(pk & 0xFF);
                        o[(2 * cp + 1) * 16] = (unsigned char)((pk >> 8) & 0xFF);
                    }
                } else {
                    unsigned short* o = (unsigned short*)H + (size_t)row * 128 + l16;
                    #pragma unroll
                    for (int ct = 0; ct < 8; ++ct)
                        o[ct * 16] = f2bf(acc[rt][ct][r]);
                }
            }
        }
    }
}

// ---------------------------------------------------------------------------
// Init: zero packed[8N u64] (as uint4) + done counter; blocks [0,64) also
// transpose+convert W1/W2 to bf16 WT1/WT2.
// ---------------------------------------------------------------------------
__global__ __launch_bounds__(256) void k_init(u64* __restrict__ packed, int n4,
                                              int* __restrict__ done,
                                              const float* __restrict__ W1,
                                              const float* __restrict__ W2,
                                              unsigned short* __restrict__ WT1,
                                              unsigned short* __restrict__ WT2) {
    int idx = blockIdx.x * 256 + threadIdx.x;
    if (idx < n4) ((uint4*)packed)[idx] = make_uint4(0u, 0u, 0u, 0u);
    if (idx == 0) *done = 0;
    if (blockIdx.x < 64) {
        int j = blockIdx.x * 256 + threadIdx.x;  // 16384 total
        int k = j >> 7, nn = j & 127;
        WT1[nn * 128 + k] = f2bf(W1[k * 128 + nn]);
        WT2[nn * 128 + k] = f2bf(W2[k * 128 + nn]);
    }
}

// ---------------------------------------------------------------------------
// Fused gemm1 + hist: blocks [0,gGemm) compute h8 = fp8(x@W1) (MFMA pipe);
// blocks [gGemm, ...) do the 8-replica u64 histogram (atomic/TCC pipe).
// Replica r = (i>>8)&7, rank[i] = per-replica arrival order (atomic return).
// ---------------------------------------------------------------------------
__global__ __launch_bounds__(256) void k_gemm1_hist(const float* __restrict__ x,
                                                    const unsigned short* __restrict__ WT1,
                                                    unsigned char* __restrict__ h8,
                                                    const int* __restrict__ dst,
                                                    const float* __restrict__ ew,
                                                    u64* __restrict__ packed,
                                                    int* __restrict__ rank,
                                                    int E, int N, int gGemm) {
    const int b = blockIdx.x;
    if (b < gGemm) {
        gemm_body<1, 1>(x, WT1, h8, N, b);
        return;
    }
    int i = (b - gGemm) * 256 + threadIdx.x;
    if (i < E) {
        int d = dst[i];
        int r = (i >> 8) & 7;
        u64 add = (1ULL << 44) + (u64)(ew[i] * 4294967296.0f);
        u64 old = atomicAdd(&packed[(size_t)r * N + d], add);
        rank[i] = (int)(old >> 44);
    }
}

// ---------------------------------------------------------------------------
// Scan (one kernel): per-1024-chunk local exclusive scan of total counts into
// rowptr, fused decode (dinv, 8x8-bit replica bases), chunk totals release-
// stored into csums; last block (done counter) wave-scans the <=64 totals
// into exclusive chunk offsets in place.
// ---------------------------------------------------------------------------
__global__ __launch_bounds__(256) void k_scan(const u64* __restrict__ packed,
                                              float* __restrict__ dinv,
                                              u64* __restrict__ bases,
                                              int* __restrict__ rowptr,
                                              int* __restrict__ csums,
                                              int* __restrict__ done, int nNodes) {
    __shared__ int s[256];
    __shared__ int lastFlag;
    const int t = threadIdx.x;
    const int base = blockIdx.x * 1024 + t * 4;
    const int n = nNodes + 1;  // scan domain: N counts + trailing 0
    int v[4];
    #pragma unroll
    for (int u = 0; u < 4; ++u) {
        int idx = base + u;
        int c = 0;
        if (idx < nNodes) {
            const u64 mask = (1ULL << 44) - 1;
            u64 ssum = 0;
            u64 bs = 0;
            uint32 cum = 0;
            #pragma unroll
            for (int r = 0; r < 8; ++r) {
                u64 pv = packed[(size_t)r * nNodes + idx];
                bs |= (u64)cum << (8 * r);  // field 0 = 0
                cum += (uint32)(pv >> 44);
                ssum += (pv & mask);
            }
            c = (int)cum;
            float deg = 1.0f + (float)ssum * (1.0f / 4294967296.0f);
            dinv[idx] = rsqrtf(deg);
            bases[idx] = bs;
        }
        v[u] = c;
    }
    s[t] = v[0] + v[1] + v[2] + v[3];
    __syncthreads();
    #pragma unroll
    for (int off = 1; off < 256; off <<= 1) {
        int x = (t >= off) ? s[t - off] : 0;
        __syncthreads();
        s[t] += x;
        __syncthreads();
    }
    if (t == 255)
        __hip_atomic_store(&csums[blockIdx.x], s[255], __ATOMIC_RELEASE,
                           __HIP_MEMORY_SCOPE_AGENT);
    int e = (t == 0) ? 0 : s[t - 1];
    if (base + 0 < n) rowptr[base + 0] = e;
    if (base + 1 < n) rowptr[base + 1] = e + v[0];
    if (base + 2 < n) rowptr[base + 2] = e + v[0] + v[1];
    if (base + 3 < n) rowptr[base + 3] = e + v[0] + v[1] + v[2];

    // last-block: exclusive scan of the gridDim.x (<=64) chunk totals
    __syncthreads();  // all stores issued (incl. t255's release store)
    if (t == 0) {
        int prev = __hip_atomic_fetch_add(done, 1, __ATOMIC_ACQ_REL,
                                          __HIP_MEMORY_SCOPE_AGENT);
        lastFlag = (prev == (int)gridDim.x - 1);
    }
    __syncthreads();
    if (lastFlag && t < 64) {
        int g = (int)gridDim.x;
        int orig = (t < g) ? __hip_atomic_load(&csums[t], __ATOMIC_ACQUIRE,
                                               __HIP_MEMORY_SCOPE_AGENT)
                           : 0;
        int vv = orig;
        #pragma unroll
        for (int off = 1; off < 64; off <<= 1) {
            int y = __shfl_up(vv, off, 64);
            if (t >= off) vv += y;
        }
        if (t < g) csums[t] = vv - orig;  // exclusive chunk offset
    }
}

// Fill CSR (atomic-free):
//   pos = rowptr_local[d] + csums[d>>10] + base_replica(d, r) + rank[e].
__global__ __launch_bounds__(256) void k_fill(const int* __restrict__ src,
                                              const int* __restrict__ dst,
                                              const float* __restrict__ ew,
                                              const float* __restrict__ dinv,
                                              const int* __restrict__ rowptr,
                                              const int* __restrict__ csums,
                                              const u64* __restrict__ bases,
                                              const int* __restrict__ rank,
                                              float2* __restrict__ csr, int e) {
    int i = blockIdx.x * 256 + threadIdx.x;
    if (i < e) {
        int s = src[i], d = dst[i];
        int r = (i >> 8) & 7;  // must match k_gemm1_hist's replica map
        float nrm = dinv[s] * ew[i] * dinv[d];
        int pos = rowptr[d] + csums[d >> 10]
                + (int)((bases[d] >> (8 * r)) & 0xFF) + rank[i];
        csr[pos] = make_float2(__int_as_float(s), nrm);
    }
}

// ---------------------------------------------------------------------------
// CSR gather helpers: 8-wide fp32 FMA from bf16 (uint4) or fp8 (uint2) rows.
// ---------------------------------------------------------------------------
__device__ __forceinline__ void fma8_bf(float* acc, uint4 u, float w) {
    float2 f;
    f = bf2_decode(u.x); acc[0] += f.x * w; acc[1] += f.y * w;
    f = bf2_decode(u.y); acc[2] += f.x * w; acc[3] += f.y * w;
    f = bf2_decode(u.z); acc[4] += f.x * w; acc[5] += f.y * w;
    f = bf2_decode(u.w); acc[6] += f.x * w; acc[7] += f.y * w;
}

__device__ __forceinline__ void fma8_f8(float* acc, uint2 u, float w) {
    f32x2 f;
    f = __builtin_amdgcn_cvt_pk_f32_fp8((int)u.x, false);
    acc[0] += f[0] * w; acc[1] += f[1] * w;
    f = __builtin_amdgcn_cvt_pk_f32_fp8((int)u.x, true);
    acc[2] += f[0] * w; acc[3] += f[1] * w;
    f = __builtin_amdgcn_cvt_pk_f32_fp8((int)u.y, false);
    acc[4] += f[0] * w; acc[5] += f[1] * w;
    f = __builtin_amdgcn_cvt_pk_f32_fp8((int)u.y, true);
    acc[6] += f[0] * w; acc[7] += f[1] * w;
}

// ---------------------------------------------------------------------------
// Fused layer-1 aggregation + layer-2 GEMM.
// Block = 256 threads (4 waves) = 32 nodes. Phase 1: wave wv gathers nodes
// [nb+wv*8, nb+wv*8+8) with the quarter-wave CSR layout (fp8 h8 rows),
// applies bias+relu, writes bf16 rows into LDS sA[32][136] (pad 8 -> row
// stride 272 B -> 2-way bank conflict on ds_read_b128 = free). Phase 2:
// barrier, then each wave computes a 32-row x 32-col slice of h2 = sA @ W2
// (2x2 16x16 tiles, K=128 in 4 steps), writing bf16 h2 directly.
// ---------------------------------------------------------------------------
__global__ __launch_bounds__(256) void k_ag2(const unsigned char* __restrict__ h8,
                                             const float2* __restrict__ csr,
                                             const int* __restrict__ rowptr,
                                             const int* __restrict__ csums,
                                             const float* __restrict__ dinv,
                                             const float4* __restrict__ bias4,
                                             const unsigned short* __restrict__ WT2,
                                             unsigned short* __restrict__ h2,
                                             int N) {
    __shared__ unsigned short sA[32][136];
    const int lane = threadIdx.x & 63;
    const int wv   = threadIdx.x >> 6;
    const int q    = lane >> 4;     // quarter (== MFMA quad later)
    const int l    = lane & 15;
    const int nb   = blockIdx.x * 32;
    const uint2* H2 = (const uint2*)h8;

    // ---- phase 1: gather 8 nodes per wave into LDS ----
    for (int j = 0; j < 8; ++j) {
        const int node = nb + wv * 8 + j;
        float acc[8] = {};
        if (node < N) {   // wave-uniform branch
            const int start = rowptr[node] + csums[node >> 10];
            const int end   = rowptr[node + 1] + csums[(node + 1) >> 10];
            float di = dinv[node];
            float selfw = (q == 0) ? di * di : 0.0f;  // self-loop once (q0)
            fma8_f8(acc, H2[(size_t)node * 16 + l], selfw);

            for (int k = start; k < end; k += 16) {  // 16 edges/iter
                float2 c[4];
                float w[4];
                #pragma unroll
                for (int jj = 0; jj < 4; ++jj) {
                    int ej = k + q + 4 * jj;
                    c[jj] = csr[ej < end ? ej : end - 1];
                    w[jj] = (ej < end) ? c[jj].y : 0.0f;
                }
                uint2 u[4];
                #pragma unroll
                for (int jj = 0; jj < 4; ++jj)
                    u[jj] = H2[(size_t)__float_as_int(c[jj].x) * 16 + l];
                #pragma unroll
                for (int jj = 0; jj < 4; ++jj) fma8_f8(acc, u[jj], w[jj]);
            }
            // combine quarters
            #pragma unroll
            for (int t = 0; t < 8; ++t) {
                acc[t] += __shfl_xor(acc[t], 16, 64);
                acc[t] += __shfl_xor(acc[t], 32, 64);
            }
        }
        if (q == 0) {  // lanes 0..15 write the bf16 row (zeros if node >= N)
            uint4 o = make_uint4(0u, 0u, 0u, 0u);
            if (node < N) {
                float4 b0 = bias4[l * 2], b1v = bias4[l * 2 + 1];
                acc[0] += b0.x;  acc[1] += b0.y;  acc[2] += b0.z;  acc[3] += b0.w;
                acc[4] += b1v.x; acc[5] += b1v.y; acc[6] += b1v.z; acc[7] += b1v.w;
                #pragma unroll
                for (int t = 0; t < 8; ++t) acc[t] = fmaxf(acc[t], 0.0f);
                o.x = (uint32)f2bf(acc[0]) | ((uint32)f2bf(acc[1]) << 16);
                o.y = (uint32)f2bf(acc[2]) | ((uint32)f2bf(acc[3]) << 16);
                o.z = (uint32)f2bf(acc[4]) | ((uint32)f2bf(acc[5]) << 16);
                o.w = (uint32)f2bf(acc[6]) | ((uint32)f2bf(acc[7]) << 16);
            }
            *(uint4*)&sA[wv * 8 + j][l * 8] = o;
        }
    }

    __syncthreads();

    // ---- phase 2: h2[nb..nb+32) = sA @ W2, wave wv owns cols [wv*32, wv*32+32) ----
    f32x4 a2[2][2] = {};
    #pragma unroll
    for (int ks = 0; ks < 4; ++ks) {
        const int k0 = ks * 32 + q * 8;
        bf16x8 a[2];
        a[0] = *(const bf16x8*)&sA[l][k0];
        a[1] = *(const bf16x8*)&sA[16 + l][k0];
        #pragma unroll
        for (int ct = 0; ct < 2; ++ct) {
            bf16x8 b = *(const bf16x8*)(WT2 + (size_t)(wv * 32 + ct * 16 + l) * 128 + k0);
            a2[0][ct] = __builtin_amdgcn_mfma_f32_16x16x32_bf16(a[0], b, a2[0][ct], 0, 0, 0);
            a2[1][ct] = __builtin_amdgcn_mfma_f32_16x16x32_bf16(a[1], b, a2[1][ct], 0, 0, 0);
        }
    }
    // D layout: col = lane&15 (within 16-tile), row = q*4 + reg
    #pragma unroll
    for (int rt = 0; rt < 2; ++rt) {
        #pragma unroll
        for (int r = 0; r < 4; ++r) {
            int row = nb + rt * 16 + q * 4 + r;
            if (row < N) {
                unsigned short* o = h2 + (size_t)row * 128 + wv * 32 + l;
                o[0]  = f2bf(a2[rt][0][r]);
                o[16] = f2bf(a2[rt][1][r]);
            }
        }
    }
}

// ---------------------------------------------------------------------------
// CSR gather, quarter-wave layout: one 64-lane wave per node; each 16-lane
// quarter reads a full feature row. Used for the final layer only
// (INFP8=0 bf16 rows, ACT=1 sigmoid -> fp32 out).
// ---------------------------------------------------------------------------
template <int INFP8, int ACT>
__global__ __launch_bounds__(256) void k_gather(const void* __restrict__ Hp,
                                                const float2* __restrict__ csr,
                                                const int* __restrict__ rowptr,
                                                const int* __restrict__ csums,
                                                const float* __restrict__ dinv,
                                                const float4* __restrict__ bias4,
                                                void* __restrict__ outp, int N) {
    int node = blockIdx.x * 4 + (threadIdx.x >> 6);
    if (node >= N) return;
    const int lane = threadIdx.x & 63;
    const int q = lane >> 4, l = lane & 15;
    const int start = rowptr[node] + csums[node >> 10];
    const int end   = rowptr[node + 1] + csums[(node + 1) >> 10];

    const uint2* H2 = (const uint2*)Hp;   // fp8 rows: 16 x 8 B
    const uint4* H4 = (const uint4*)Hp;   // bf16 rows: 16 x 16 B

    // self-loop (ew=1, norm=dinv^2): counted once, via quarter 0 only
    float di = dinv[node];
    float selfw = (q == 0) ? di * di : 0.0f;
    float acc[8] = {};
    if (INFP8) fma8_f8(acc, H2[(size_t)node * 16 + l], selfw);
    else       fma8_bf(acc, H4[(size_t)node * 16 + l], selfw);

    for (int k = start; k < end; k += 16) {  // 16 edges/iter across quarters
        float2 c[4];
        float w[4];
        #pragma unroll
        for (int j = 0; j < 4; ++j) {
            int ej = k + q + 4 * j;
            c[j] = csr[ej < end ? ej : end - 1];
            w[j] = (ej < end) ? c[j].y : 0.0f;
        }
        if (INFP8) {
            uint2 u[4];
            #pragma unroll
            for (int j = 0; j < 4; ++j)
                u[j] = H2[(size_t)__float_as_int(c[j].x) * 16 + l];
            #pragma unroll
            for (int j = 0; j < 4; ++j) fma8_f8(acc, u[j], w[j]);
        } else {
            uint4 u[4];
            #pragma unroll
            for (int j = 0; j < 4; ++j)
                u[j] = H4[(size_t)__float_as_int(c[j].x) * 16 + l];
            #pragma unroll
            for (int j = 0; j < 4; ++j) fma8_bf(acc, u[j], w[j]);
        }
    }

    // combine quarters: after xor-16 and xor-32 every lane holds the total
    #pragma unroll
    for (int j = 0; j < 8; ++j) {
        acc[j] += __shfl_xor(acc[j], 16, 64);
        acc[j] += __shfl_xor(acc[j], 32, 64);
    }

    if (q == 0) {  // lanes 0..15 write the row
        float4 b0 = bias4[l * 2], b1 = bias4[l * 2 + 1];
        acc[0] += b0.x; acc[1] += b0.y; acc[2] += b0.z; acc[3] += b0.w;
        acc[4] += b1.x; acc[5] += b1.y; acc[6] += b1.z; acc[7] += b1.w;
        if (ACT == 0) {
            #pragma unroll
            for (int j = 0; j < 8; ++j) acc[j] = fmaxf(acc[j], 0.0f);
            uint4 o;
            o.x = (uint32)f2bf(acc[0]) | ((uint32)f2bf(acc[1]) << 16);
            o.y = (uint32)f2bf(acc[2]) | ((uint32)f2bf(acc[3]) << 16);
            o.z = (uint32)f2bf(acc[4]) | ((uint32)f2bf(acc[5]) << 16);
            o.w = (uint32)f2bf(acc[6]) | ((uint32)f2bf(acc[7]) << 16);
            ((uint4*)outp)[(size_t)node * 16 + l] = o;
        } else {
            #pragma unroll
            for (int j = 0; j < 8; ++j) acc[j] = 1.0f / (1.0f + expf(-acc[j]));
            float4* o4 = (float4*)outp + (size_t)node * 32 + l * 2;
            o4[0] = make_float4(acc[0], acc[1], acc[2], acc[3]);
            o4[1] = make_float4(acc[4], acc[5], acc[6], acc[7]);
        }
    }
}

extern "C" void kernel_launch(void* const* d_in, const int* in_sizes, int n_in,
                              void* d_out, int out_size, void* d_ws, size_t ws_size,
                              hipStream_t stream) {
    const float* x  = (const float*)d_in[0];
    const int*   ei = (const int*)d_in[1];
    const float* ew = (const float*)d_in[2];
    const float* W1 = (const float*)d_in[3];
    const float* b1 = (const float*)d_in[4];
    const float* W2 = (const float*)d_in[5];
    const float* b2 = (const float*)d_in[6];

    const int N = in_sizes[0] / 128;
    const int E = in_sizes[2];
    const int* src = ei;
    const int* dst = ei + E;
    float* out = (float*)d_out;

    // Workspace layout (256B-aligned slabs):
    //   dinv [N] | rowptr [N+1] | csums [1024] | done | bases [N u64]
    //   | WT1 | WT2 | rank [E] | csr [E f2] | h8 [N*128 fp8]
    //   | h2 [N*128 bf16]
    //   (packed u64[8N] aliases h2: dead after k_scan, h2 written at k_ag2)
    auto align = [](size_t v) { return (v + 255) & ~(size_t)255; };
    char* p = (char*)d_ws;
    float*  dinv   = (float*)p;   p += align((size_t)N * 4);
    int*    rowptr = (int*)p;     p += align((size_t)(N + 1) * 4);
    int*    csums  = (int*)p;     p += align((size_t)1024 * 4);
    int*    done   = (int*)p;     p += align((size_t)256);
    u64*    bases  = (u64*)p;     p += align((size_t)N * 8);
    unsigned short* WT1 = (unsigned short*)p; p += align((size_t)128 * 128 * 2);
    unsigned short* WT2 = (unsigned short*)p; p += align((size_t)128 * 128 * 2);
    int*    rank   = (int*)p;     p += align((size_t)E * 4);
    float2* csr    = (float2*)p;  p += align((size_t)E * 8);
    unsigned char*  h8 = (unsigned char*)p;  p += align((size_t)N * 128);
    unsigned short* h2 = (unsigned short*)p;
    u64* packed = (u64*)h2;  // alias (8N u64 = 3.2 MB < 12.8 MB; dead after scan)

    const int nbE = (E + 255) / 256;
    const int gScan = (N + 1 + 1023) / 1024;   // 49 for N=50000 (<=64 required)
    const int gGemm = (N + 127) / 128;
    const int gGath = (N + 3) / 4;
    const int gAg2  = (N + 31) / 32;
    const int n4 = N * 4;                      // 8N u64 = 4N uint4
    const int gInit = ((n4 + 255) / 256) < 64 ? 64 : ((n4 + 255) / 256);

    // --- Build (+ layer-1 GEMM overlapped with hist) ---
    k_init<<<gInit, 256, 0, stream>>>(packed, n4, done, W1, W2, WT1, WT2);
    k_gemm1_hist<<<gGemm + nbE, 256, 0, stream>>>(x, WT1, h8, dst, ew, packed,
                                                  rank, E, N, gGemm);
    k_scan<<<gScan, 256, 0, stream>>>(packed, dinv, bases, rowptr, csums, done, N);
    k_fill<<<nbE, 256, 0, stream>>>(src, dst, ew, dinv, rowptr, csums, bases,
                                    rank, csr, E);

    // --- Fused: g1 = relu(gather(h8)+b1) in LDS ; h2 = bf16(g1@W2) ---
    k_ag2<<<gAg2, 256, 0, stream>>>(h8, csr, rowptr, csums, dinv,
                                    (const float4*)b1, WT2, h2, N);

    // --- out = sigmoid(gather(h2) + b2) ---
    k_gather<0, 1><<<gGath, 256, 0, stream>>>(h2, csr, rowptr, csums,
                                              dinv, (const float4*)b2, out, N);
}

// Round 2
// 210.251 us; speedup vs baseline: 1.0190x; 1.0190x over previous
//
#include <hip/hip_runtime.h>
#include <math.h>

// ---------------------------------------------------------------------------
// GCN 2-layer forward on MI355X.
// Round 14: k_ag2 re-tiled for occupancy. R13's 32-node/8-per-wave block left
// the fused gather latency-starved (Occ 31%, 1563 blocks, 8-node serial chain
// per wave). Now 16 nodes/block (4 waves x 4 nodes serial), grid 3125 ->
// 8 blocks/CU resident (32 waves/CU), half the dependent-load chain per wave.
// MFMA phase is a single 16x128 tile (wave wv owns cols [wv*32,wv*32+32)).
// Everything else unchanged from R13.
// ---------------------------------------------------------------------------

typedef unsigned int uint32;
typedef unsigned long long u64;
typedef __attribute__((ext_vector_type(8))) short bf16x8;   // 8 bf16 (4 VGPRs)
typedef __attribute__((ext_vector_type(4))) float f32x4;
typedef __attribute__((ext_vector_type(2))) float f32x2;

__device__ __forceinline__ unsigned short f2bf(float f) {   // RNE fp32->bf16
    uint32 b = __float_as_uint(f);
    return (unsigned short)((b + 0x7FFFu + ((b >> 16) & 1u)) >> 16);
}

__device__ __forceinline__ float2 bf2_decode(uint32 u) {
    return make_float2(__uint_as_float(u << 16),
                       __uint_as_float(u & 0xFFFF0000u));
}

// ---------------------------------------------------------------------------
// MFMA GEMM body: H[n x 128] = A[n x 128] @ W (WT bf16 transposed).
// 256 threads = 4 waves; each wave 32 rows x 128 cols (2x8 16x16 tiles),
// K=128 in 4 steps. AFP32: A fp32 (converted inline) vs bf16.
// OUTFP8: D written as fp8 e4m3 bytes vs bf16.
// ---------------------------------------------------------------------------
template <int AFP32, int OUTFP8>
__device__ __forceinline__ void gemm_body(const void* __restrict__ Ap,
                                          const unsigned short* __restrict__ WT,
                                          void* __restrict__ H,
                                          int n, int tb) {
    const int lane = threadIdx.x & 63;
    const int wv   = threadIdx.x >> 6;
    const int quad = lane >> 4;
    const int l16  = lane & 15;
    const int m0   = tb * 128 + wv * 32;
    f32x4 acc[2][8] = {};

    #pragma unroll
    for (int ks = 0; ks < 4; ++ks) {
        const int k0 = ks * 32 + quad * 8;
        bf16x8 a[2];
        #pragma unroll
        for (int rt = 0; rt < 2; ++rt) {
            int row = m0 + rt * 16 + l16;
            if (row >= n) row = n - 1;  // clamp; stores are guarded
            if (AFP32) {
                const float* Af = (const float*)Ap + (size_t)row * 128 + k0;
                float4 f0 = *(const float4*)(Af);
                float4 f1 = *(const float4*)(Af + 4);
                bf16x8 v;
                v[0] = (short)f2bf(f0.x); v[1] = (short)f2bf(f0.y);
                v[2] = (short)f2bf(f0.z); v[3] = (short)f2bf(f0.w);
                v[4] = (short)f2bf(f1.x); v[5] = (short)f2bf(f1.y);
                v[6] = (short)f2bf(f1.z); v[7] = (short)f2bf(f1.w);
                a[rt] = v;
            } else {
                const unsigned short* Ab = (const unsigned short*)Ap + (size_t)row * 128 + k0;
                a[rt] = *(const bf16x8*)Ab;
            }
        }
        #pragma unroll
        for (int ct = 0; ct < 8; ++ct) {
            bf16x8 b = *(const bf16x8*)(WT + (size_t)(ct * 16 + l16) * 128 + k0);
            acc[0][ct] = __builtin_amdgcn_mfma_f32_16x16x32_bf16(a[0], b, acc[0][ct], 0, 0, 0);
            acc[1][ct] = __builtin_amdgcn_mfma_f32_16x16x32_bf16(a[1], b, acc[1][ct], 0, 0, 0);
        }
    }

    // D layout: col = lane&15, row = quad*4 + reg  (m89-verified)
    #pragma unroll
    for (int rt = 0; rt < 2; ++rt) {
        #pragma unroll
        for (int r = 0; r < 4; ++r) {
            int row = m0 + rt * 16 + quad * 4 + r;
            if (row < n) {
                if (OUTFP8) {
                    unsigned char* o = (unsigned char*)H + (size_t)row * 128 + l16;
                    #pragma unroll
                    for (int cp = 0; cp < 4; ++cp) {
                        int pk = __builtin_amdgcn_cvt_pk_fp8_f32(
                            acc[rt][2 * cp][r], acc[rt][2 * cp + 1][r], 0, false);
                        o[(2 * cp) * 16]     = (unsigned char)(pk & 0xFF);
                        o[(2 * cp + 1) * 16] = (unsigned char)((pk >> 8) & 0xFF);
                    }
                } else {
                    unsigned short* o = (unsigned short*)H + (size_t)row * 128 + l16;
                    #pragma unroll
                    for (int ct = 0; ct < 8; ++ct)
                        o[ct * 16] = f2bf(acc[rt][ct][r]);
                }
            }
        }
    }
}

// ---------------------------------------------------------------------------
// Init: zero packed[8N u64] (as uint4) + done counter; blocks [0,64) also
// transpose+convert W1/W2 to bf16 WT1/WT2.
// ---------------------------------------------------------------------------
__global__ __launch_bounds__(256) void k_init(u64* __restrict__ packed, int n4,
                                              int* __restrict__ done,
                                              const float* __restrict__ W1,
                                              const float* __restrict__ W2,
                                              unsigned short* __restrict__ WT1,
                                              unsigned short* __restrict__ WT2) {
    int idx = blockIdx.x * 256 + threadIdx.x;
    if (idx < n4) ((uint4*)packed)[idx] = make_uint4(0u, 0u, 0u, 0u);
    if (idx == 0) *done = 0;
    if (blockIdx.x < 64) {
        int j = blockIdx.x * 256 + threadIdx.x;  // 16384 total
        int k = j >> 7, nn = j & 127;
        WT1[nn * 128 + k] = f2bf(W1[k * 128 + nn]);
        WT2[nn * 128 + k] = f2bf(W2[k * 128 + nn]);
    }
}

// ---------------------------------------------------------------------------
// Fused gemm1 + hist: blocks [0,gGemm) compute h8 = fp8(x@W1) (MFMA pipe);
// blocks [gGemm, ...) do the 8-replica u64 histogram (atomic/TCC pipe).
// Replica r = (i>>8)&7, rank[i] = per-replica arrival order (atomic return).
// ---------------------------------------------------------------------------
__global__ __launch_bounds__(256) void k_gemm1_hist(const float* __restrict__ x,
                                                    const unsigned short* __restrict__ WT1,
                                                    unsigned char* __restrict__ h8,
                                                    const int* __restrict__ dst,
                                                    const float* __restrict__ ew,
                                                    u64* __restrict__ packed,
                                                    int* __restrict__ rank,
                                                    int E, int N, int gGemm) {
    const int b = blockIdx.x;
    if (b < gGemm) {
        gemm_body<1, 1>(x, WT1, h8, N, b);
        return;
    }
    int i = (b - gGemm) * 256 + threadIdx.x;
    if (i < E) {
        int d = dst[i];
        int r = (i >> 8) & 7;
        u64 add = (1ULL << 44) + (u64)(ew[i] * 4294967296.0f);
        u64 old = atomicAdd(&packed[(size_t)r * N + d], add);
        rank[i] = (int)(old >> 44);
    }
}

// ---------------------------------------------------------------------------
// Scan (one kernel): per-1024-chunk local exclusive scan of total counts into
// rowptr, fused decode (dinv, 8x8-bit replica bases), chunk totals release-
// stored into csums; last block (done counter) wave-scans the <=64 totals
// into exclusive chunk offsets in place.
// ---------------------------------------------------------------------------
__global__ __launch_bounds__(256) void k_scan(const u64* __restrict__ packed,
                                              float* __restrict__ dinv,
                                              u64* __restrict__ bases,
                                              int* __restrict__ rowptr,
                                              int* __restrict__ csums,
                                              int* __restrict__ done, int nNodes) {
    __shared__ int s[256];
    __shared__ int lastFlag;
    const int t = threadIdx.x;
    const int base = blockIdx.x * 1024 + t * 4;
    const int n = nNodes + 1;  // scan domain: N counts + trailing 0
    int v[4];
    #pragma unroll
    for (int u = 0; u < 4; ++u) {
        int idx = base + u;
        int c = 0;
        if (idx < nNodes) {
            const u64 mask = (1ULL << 44) - 1;
            u64 ssum = 0;
            u64 bs = 0;
            uint32 cum = 0;
            #pragma unroll
            for (int r = 0; r < 8; ++r) {
                u64 pv = packed[(size_t)r * nNodes + idx];
                bs |= (u64)cum << (8 * r);  // field 0 = 0
                cum += (uint32)(pv >> 44);
                ssum += (pv & mask);
            }
            c = (int)cum;
            float deg = 1.0f + (float)ssum * (1.0f / 4294967296.0f);
            dinv[idx] = rsqrtf(deg);
            bases[idx] = bs;
        }
        v[u] = c;
    }
    s[t] = v[0] + v[1] + v[2] + v[3];
    __syncthreads();
    #pragma unroll
    for (int off = 1; off < 256; off <<= 1) {
        int x = (t >= off) ? s[t - off] : 0;
        __syncthreads();
        s[t] += x;
        __syncthreads();
    }
    if (t == 255)
        __hip_atomic_store(&csums[blockIdx.x], s[255], __ATOMIC_RELEASE,
                           __HIP_MEMORY_SCOPE_AGENT);
    int e = (t == 0) ? 0 : s[t - 1];
    if (base + 0 < n) rowptr[base + 0] = e;
    if (base + 1 < n) rowptr[base + 1] = e + v[0];
    if (base + 2 < n) rowptr[base + 2] = e + v[0] + v[1];
    if (base + 3 < n) rowptr[base + 3] = e + v[0] + v[1] + v[2];

    // last-block: exclusive scan of the gridDim.x (<=64) chunk totals
    __syncthreads();  // all stores issued (incl. t255's release store)
    if (t == 0) {
        int prev = __hip_atomic_fetch_add(done, 1, __ATOMIC_ACQ_REL,
                                          __HIP_MEMORY_SCOPE_AGENT);
        lastFlag = (prev == (int)gridDim.x - 1);
    }
    __syncthreads();
    if (lastFlag && t < 64) {
        int g = (int)gridDim.x;
        int orig = (t < g) ? __hip_atomic_load(&csums[t], __ATOMIC_ACQUIRE,
                                               __HIP_MEMORY_SCOPE_AGENT)
                           : 0;
        int vv = orig;
        #pragma unroll
        for (int off = 1; off < 64; off <<= 1) {
            int y = __shfl_up(vv, off, 64);
            if (t >= off) vv += y;
        }
        if (t < g) csums[t] = vv - orig;  // exclusive chunk offset
    }
}

// Fill CSR (atomic-free):
//   pos = rowptr_local[d] + csums[d>>10] + base_replica(d, r) + rank[e].
__global__ __launch_bounds__(256) void k_fill(const int* __restrict__ src,
                                              const int* __restrict__ dst,
                                              const float* __restrict__ ew,
                                              const float* __restrict__ dinv,
                                              const int* __restrict__ rowptr,
                                              const int* __restrict__ csums,
                                              const u64* __restrict__ bases,
                                              const int* __restrict__ rank,
                                              float2* __restrict__ csr, int e) {
    int i = blockIdx.x * 256 + threadIdx.x;
    if (i < e) {
        int s = src[i], d = dst[i];
        int r = (i >> 8) & 7;  // must match k_gemm1_hist's replica map
        float nrm = dinv[s] * ew[i] * dinv[d];
        int pos = rowptr[d] + csums[d >> 10]
                + (int)((bases[d] >> (8 * r)) & 0xFF) + rank[i];
        csr[pos] = make_float2(__int_as_float(s), nrm);
    }
}

// ---------------------------------------------------------------------------
// CSR gather helpers: 8-wide fp32 FMA from bf16 (uint4) or fp8 (uint2) rows.
// ---------------------------------------------------------------------------
__device__ __forceinline__ void fma8_bf(float* acc, uint4 u, float w) {
    float2 f;
    f = bf2_decode(u.x); acc[0] += f.x * w; acc[1] += f.y * w;
    f = bf2_decode(u.y); acc[2] += f.x * w; acc[3] += f.y * w;
    f = bf2_decode(u.z); acc[4] += f.x * w; acc[5] += f.y * w;
    f = bf2_decode(u.w); acc[6] += f.x * w; acc[7] += f.y * w;
}

__device__ __forceinline__ void fma8_f8(float* acc, uint2 u, float w) {
    f32x2 f;
    f = __builtin_amdgcn_cvt_pk_f32_fp8((int)u.x, false);
    acc[0] += f[0] * w; acc[1] += f[1] * w;
    f = __builtin_amdgcn_cvt_pk_f32_fp8((int)u.x, true);
    acc[2] += f[0] * w; acc[3] += f[1] * w;
    f = __builtin_amdgcn_cvt_pk_f32_fp8((int)u.y, false);
    acc[4] += f[0] * w; acc[5] += f[1] * w;
    f = __builtin_amdgcn_cvt_pk_f32_fp8((int)u.y, true);
    acc[6] += f[0] * w; acc[7] += f[1] * w;
}

// ---------------------------------------------------------------------------
// Fused layer-1 aggregation + layer-2 GEMM.
// Block = 256 threads (4 waves) = 16 nodes. Phase 1: wave wv gathers nodes
// [nb+wv*4, nb+wv*4+4) with the quarter-wave CSR layout (fp8 h8 rows),
// applies bias+relu, writes bf16 rows into LDS sA[16][136] (pad 8 -> row
// stride 272 B -> 2-way bank conflict on ds_read_b128 = free). Phase 2:
// barrier, then each wave computes the 16-row x 32-col slice of h2 = sA @ W2
// at cols [wv*32, wv*32+32) (2 16x16 tiles, K=128 in 4 steps), bf16 out.
// Grid = N/16 = 3125 blocks -> 8 blocks/CU resident, full 32 waves/CU.
// ---------------------------------------------------------------------------
__global__ __launch_bounds__(256) void k_ag2(const unsigned char* __restrict__ h8,
                                             const float2* __restrict__ csr,
                                             const int* __restrict__ rowptr,
                                             const int* __restrict__ csums,
                                             const float* __restrict__ dinv,
                                             const float4* __restrict__ bias4,
                                             const unsigned short* __restrict__ WT2,
                                             unsigned short* __restrict__ h2,
                                             int N) {
    __shared__ unsigned short sA[16][136];
    const int lane = threadIdx.x & 63;
    const int wv   = threadIdx.x >> 6;
    const int q    = lane >> 4;     // quarter (== MFMA quad later)
    const int l    = lane & 15;
    const int nb   = blockIdx.x * 16;
    const uint2* H2 = (const uint2*)h8;

    // ---- phase 1: gather 4 nodes per wave into LDS ----
    for (int j = 0; j < 4; ++j) {
        const int node = nb + wv * 4 + j;
        float acc[8] = {};
        if (node < N) {   // wave-uniform branch
            const int start = rowptr[node] + csums[node >> 10];
            const int end   = rowptr[node + 1] + csums[(node + 1) >> 10];
            float di = dinv[node];
            float selfw = (q == 0) ? di * di : 0.0f;  // self-loop once (q0)
            fma8_f8(acc, H2[(size_t)node * 16 + l], selfw);

            for (int k = start; k < end; k += 16) {  // 16 edges/iter
                float2 c[4];
                float w[4];
                #pragma unroll
                for (int jj = 0; jj < 4; ++jj) {
                    int ej = k + q + 4 * jj;
                    c[jj] = csr[ej < end ? ej : end - 1];
                    w[jj] = (ej < end) ? c[jj].y : 0.0f;
                }
                uint2 u[4];
                #pragma unroll
                for (int jj = 0; jj < 4; ++jj)
                    u[jj] = H2[(size_t)__float_as_int(c[jj].x) * 16 + l];
                #pragma unroll
                for (int jj = 0; jj < 4; ++jj) fma8_f8(acc, u[jj], w[jj]);
            }
            // combine quarters
            #pragma unroll
            for (int t = 0; t < 8; ++t) {
                acc[t] += __shfl_xor(acc[t], 16, 64);
                acc[t] += __shfl_xor(acc[t], 32, 64);
            }
        }
        if (q == 0) {  // lanes 0..15 write the bf16 row (zeros if node >= N)
            uint4 o = make_uint4(0u, 0u, 0u, 0u);
            if (node < N) {
                float4 b0 = bias4[l * 2], b1v = bias4[l * 2 + 1];
                acc[0] += b0.x;  acc[1] += b0.y;  acc[2] += b0.z;  acc[3] += b0.w;
                acc[4] += b1v.x; acc[5] += b1v.y; acc[6] += b1v.z; acc[7] += b1v.w;
                #pragma unroll
                for (int t = 0; t < 8; ++t) acc[t] = fmaxf(acc[t], 0.0f);
                o.x = (uint32)f2bf(acc[0]) | ((uint32)f2bf(acc[1]) << 16);
                o.y = (uint32)f2bf(acc[2]) | ((uint32)f2bf(acc[3]) << 16);
                o.z = (uint32)f2bf(acc[4]) | ((uint32)f2bf(acc[5]) << 16);
                o.w = (uint32)f2bf(acc[6]) | ((uint32)f2bf(acc[7]) << 16);
            }
            *(uint4*)&sA[wv * 4 + j][l * 8] = o;
        }
    }

    __syncthreads();

    // ---- phase 2: h2[nb..nb+16) = sA @ W2, wave wv owns cols [wv*32, wv*32+32) ----
    f32x4 a2[2] = {};
    #pragma unroll
    for (int ks = 0; ks < 4; ++ks) {
        const int k0 = ks * 32 + q * 8;
        bf16x8 a = *(const bf16x8*)&sA[l][k0];
        #pragma unroll
        for (int ct = 0; ct < 2; ++ct) {
            bf16x8 b = *(const bf16x8*)(WT2 + (size_t)(wv * 32 + ct * 16 + l) * 128 + k0);
            a2[ct] = __builtin_amdgcn_mfma_f32_16x16x32_bf16(a, b, a2[ct], 0, 0, 0);
        }
    }
    // D layout: col = lane&15 (within 16-tile), row = q*4 + reg
    #pragma unroll
    for (int r = 0; r < 4; ++r) {
        int row = nb + q * 4 + r;
        if (row < N) {
            unsigned short* o = h2 + (size_t)row * 128 + wv * 32 + l;
            o[0]  = f2bf(a2[0][r]);
            o[16] = f2bf(a2[1][r]);
        }
    }
}

// ---------------------------------------------------------------------------
// CSR gather, quarter-wave layout: one 64-lane wave per node; each 16-lane
// quarter reads a full feature row. Used for the final layer only
// (INFP8=0 bf16 rows, ACT=1 sigmoid -> fp32 out).
// ---------------------------------------------------------------------------
template <int INFP8, int ACT>
__global__ __launch_bounds__(256) void k_gather(const void* __restrict__ Hp,
                                                const float2* __restrict__ csr,
                                                const int* __restrict__ rowptr,
                                                const int* __restrict__ csums,
                                                const float* __restrict__ dinv,
                                                const float4* __restrict__ bias4,
                                                void* __restrict__ outp, int N) {
    int node = blockIdx.x * 4 + (threadIdx.x >> 6);
    if (node >= N) return;
    const int lane = threadIdx.x & 63;
    const int q = lane >> 4, l = lane & 15;
    const int start = rowptr[node] + csums[node >> 10];
    const int end   = rowptr[node + 1] + csums[(node + 1) >> 10];

    const uint2* H2 = (const uint2*)Hp;   // fp8 rows: 16 x 8 B
    const uint4* H4 = (const uint4*)Hp;   // bf16 rows: 16 x 16 B

    // self-loop (ew=1, norm=dinv^2): counted once, via quarter 0 only
    float di = dinv[node];
    float selfw = (q == 0) ? di * di : 0.0f;
    float acc[8] = {};
    if (INFP8) fma8_f8(acc, H2[(size_t)node * 16 + l], selfw);
    else       fma8_bf(acc, H4[(size_t)node * 16 + l], selfw);

    for (int k = start; k < end; k += 16) {  // 16 edges/iter across quarters
        float2 c[4];
        float w[4];
        #pragma unroll
        for (int j = 0; j < 4; ++j) {
            int ej = k + q + 4 * j;
            c[j] = csr[ej < end ? ej : end - 1];
            w[j] = (ej < end) ? c[j].y : 0.0f;
        }
        if (INFP8) {
            uint2 u[4];
            #pragma unroll
            for (int j = 0; j < 4; ++j)
                u[j] = H2[(size_t)__float_as_int(c[j].x) * 16 + l];
            #pragma unroll
            for (int j = 0; j < 4; ++j) fma8_f8(acc, u[j], w[j]);
        } else {
            uint4 u[4];
            #pragma unroll
            for (int j = 0; j < 4; ++j)
                u[j] = H4[(size_t)__float_as_int(c[j].x) * 16 + l];
            #pragma unroll
            for (int j = 0; j < 4; ++j) fma8_bf(acc, u[j], w[j]);
        }
    }

    // combine quarters: after xor-16 and xor-32 every lane holds the total
    #pragma unroll
    for (int j = 0; j < 8; ++j) {
        acc[j] += __shfl_xor(acc[j], 16, 64);
        acc[j] += __shfl_xor(acc[j], 32, 64);
    }

    if (q == 0) {  // lanes 0..15 write the row
        float4 b0 = bias4[l * 2], b1 = bias4[l * 2 + 1];
        acc[0] += b0.x; acc[1] += b0.y; acc[2] += b0.z; acc[3] += b0.w;
        acc[4] += b1.x; acc[5] += b1.y; acc[6] += b1.z; acc[7] += b1.w;
        if (ACT == 0) {
            #pragma unroll
            for (int j = 0; j < 8; ++j) acc[j] = fmaxf(acc[j], 0.0f);
            uint4 o;
            o.x = (uint32)f2bf(acc[0]) | ((uint32)f2bf(acc[1]) << 16);
            o.y = (uint32)f2bf(acc[2]) | ((uint32)f2bf(acc[3]) << 16);
            o.z = (uint32)f2bf(acc[4]) | ((uint32)f2bf(acc[5]) << 16);
            o.w = (uint32)f2bf(acc[6]) | ((uint32)f2bf(acc[7]) << 16);
            ((uint4*)outp)[(size_t)node * 16 + l] = o;
        } else {
            #pragma unroll
            for (int j = 0; j < 8; ++j) acc[j] = 1.0f / (1.0f + expf(-acc[j]));
            float4* o4 = (float4*)outp + (size_t)node * 32 + l * 2;
            o4[0] = make_float4(acc[0], acc[1], acc[2], acc[3]);
            o4[1] = make_float4(acc[4], acc[5], acc[6], acc[7]);
        }
    }
}

extern "C" void kernel_launch(void* const* d_in, const int* in_sizes, int n_in,
                              void* d_out, int out_size, void* d_ws, size_t ws_size,
                              hipStream_t stream) {
    const float* x  = (const float*)d_in[0];
    const int*   ei = (const int*)d_in[1];
    const float* ew = (const float*)d_in[2];
    const float* W1 = (const float*)d_in[3];
    const float* b1 = (const float*)d_in[4];
    const float* W2 = (const float*)d_in[5];
    const float* b2 = (const float*)d_in[6];

    const int N = in_sizes[0] / 128;
    const int E = in_sizes[2];
    const int* src = ei;
    const int* dst = ei + E;
    float* out = (float*)d_out;

    // Workspace layout (256B-aligned slabs):
    //   dinv [N] | rowptr [N+1] | csums [1024] | done | bases [N u64]
    //   | WT1 | WT2 | rank [E] | csr [E f2] | h8 [N*128 fp8]
    //   | h2 [N*128 bf16]
    //   (packed u64[8N] aliases h2: dead after k_scan, h2 written at k_ag2)
    auto align = [](size_t v) { return (v + 255) & ~(size_t)255; };
    char* p = (char*)d_ws;
    float*  dinv   = (float*)p;   p += align((size_t)N * 4);
    int*    rowptr = (int*)p;     p += align((size_t)(N + 1) * 4);
    int*    csums  = (int*)p;     p += align((size_t)1024 * 4);
    int*    done   = (int*)p;     p += align((size_t)256);
    u64*    bases  = (u64*)p;     p += align((size_t)N * 8);
    unsigned short* WT1 = (unsigned short*)p; p += align((size_t)128 * 128 * 2);
    unsigned short* WT2 = (unsigned short*)p; p += align((size_t)128 * 128 * 2);
    int*    rank   = (int*)p;     p += align((size_t)E * 4);
    float2* csr    = (float2*)p;  p += align((size_t)E * 8);
    unsigned char*  h8 = (unsigned char*)p;  p += align((size_t)N * 128);
    unsigned short* h2 = (unsigned short*)p;
    u64* packed = (u64*)h2;  // alias (8N u64 = 3.2 MB < 12.8 MB; dead after scan)

    const int nbE = (E + 255) / 256;
    const int gScan = (N + 1 + 1023) / 1024;   // 49 for N=50000 (<=64 required)
    const int gGemm = (N + 127) / 128;
    const int gGath = (N + 3) / 4;
    const int gAg2  = (N + 15) / 16;
    const int n4 = N * 4;                      // 8N u64 = 4N uint4
    const int gInit = ((n4 + 255) / 256) < 64 ? 64 : ((n4 + 255) / 256);

    // --- Build (+ layer-1 GEMM overlapped with hist) ---
    k_init<<<gInit, 256, 0, stream>>>(packed, n4, done, W1, W2, WT1, WT2);
    k_gemm1_hist<<<gGemm + nbE, 256, 0, stream>>>(x, WT1, h8, dst, ew, packed,
                                                  rank, E, N, gGemm);
    k_scan<<<gScan, 256, 0, stream>>>(packed, dinv, bases, rowptr, csums, done, N);
    k_fill<<<nbE, 256, 0, stream>>>(src, dst, ew, dinv, rowptr, csums, bases,
                                    rank, csr, E);

    // --- Fused: g1 = relu(gather(h8)+b1) in LDS ; h2 = bf16(g1@W2) ---
    k_ag2<<<gAg2, 256, 0, stream>>>(h8, csr, rowptr, csums, dinv,
                                    (const float4*)b1, WT2, h2, N);

    // --- out = sigmoid(gather(h2) + b2) ---
    k_gather<0, 1><<<gGath, 256, 0, stream>>>(h2, csr, rowptr, csums,
                                              dinv, (const float4*)b2, out, N);
}

// Round 3
// 201.457 us; speedup vs baseline: 1.0635x; 1.0437x over previous
//
#include <hip/hip_runtime.h>
#include <math.h>

// ---------------------------------------------------------------------------
// GCN 2-layer forward on MI355X.
// Round 15: layer-2 restructured as aggregate-then-GEMM (agg is linear:
// agg(g1)@W2 == agg(g1@W2)). g table stored fp8 e4m3 (noise path ~0.036x:
// agg2 0.5 x gemm2 0.29 x sigmoid 0.25 - same attenuation as h8's, verified
// safe in R12). Halves the dominant random-gather footprint (12.8 MB bf16
// h2 -> 6.4 MB fp8 g8, 256 B -> 128 B rows) and deletes the h2 write.
// Pipeline: init | gemm1+hist | scan | fill | ag1 (gather h8 -> g8 fp8)
//           | ag2s (gather g8 -> LDS bf16 -> MFMA xW2 + b2 -> sigmoid -> out).
// ---------------------------------------------------------------------------

typedef unsigned int uint32;
typedef unsigned long long u64;
typedef __attribute__((ext_vector_type(8))) short bf16x8;   // 8 bf16 (4 VGPRs)
typedef __attribute__((ext_vector_type(4))) float f32x4;
typedef __attribute__((ext_vector_type(2))) float f32x2;

__device__ __forceinline__ unsigned short f2bf(float f) {   // RNE fp32->bf16
    uint32 b = __float_as_uint(f);
    return (unsigned short)((b + 0x7FFFu + ((b >> 16) & 1u)) >> 16);
}

// ---------------------------------------------------------------------------
// MFMA GEMM body: H[n x 128] = A[n x 128] @ W (WT bf16 transposed).
// 256 threads = 4 waves; each wave 32 rows x 128 cols (2x8 16x16 tiles),
// K=128 in 4 steps. AFP32: A fp32 (converted inline) vs bf16.
// OUTFP8: D written as fp8 e4m3 bytes vs bf16.
// ---------------------------------------------------------------------------
template <int AFP32, int OUTFP8>
__device__ __forceinline__ void gemm_body(const void* __restrict__ Ap,
                                          const unsigned short* __restrict__ WT,
                                          void* __restrict__ H,
                                          int n, int tb) {
    const int lane = threadIdx.x & 63;
    const int wv   = threadIdx.x >> 6;
    const int quad = lane >> 4;
    const int l16  = lane & 15;
    const int m0   = tb * 128 + wv * 32;
    f32x4 acc[2][8] = {};

    #pragma unroll
    for (int ks = 0; ks < 4; ++ks) {
        const int k0 = ks * 32 + quad * 8;
        bf16x8 a[2];
        #pragma unroll
        for (int rt = 0; rt < 2; ++rt) {
            int row = m0 + rt * 16 + l16;
            if (row >= n) row = n - 1;  // clamp; stores are guarded
            if (AFP32) {
                const float* Af = (const float*)Ap + (size_t)row * 128 + k0;
                float4 f0 = *(const float4*)(Af);
                float4 f1 = *(const float4*)(Af + 4);
                bf16x8 v;
                v[0] = (short)f2bf(f0.x); v[1] = (short)f2bf(f0.y);
                v[2] = (short)f2bf(f0.z); v[3] = (short)f2bf(f0.w);
                v[4] = (short)f2bf(f1.x); v[5] = (short)f2bf(f1.y);
                v[6] = (short)f2bf(f1.z); v[7] = (short)f2bf(f1.w);
                a[rt] = v;
            } else {
                const unsigned short* Ab = (const unsigned short*)Ap + (size_t)row * 128 + k0;
                a[rt] = *(const bf16x8*)Ab;
            }
        }
        #pragma unroll
        for (int ct = 0; ct < 8; ++ct) {
            bf16x8 b = *(const bf16x8*)(WT + (size_t)(ct * 16 + l16) * 128 + k0);
            acc[0][ct] = __builtin_amdgcn_mfma_f32_16x16x32_bf16(a[0], b, acc[0][ct], 0, 0, 0);
            acc[1][ct] = __builtin_amdgcn_mfma_f32_16x16x32_bf16(a[1], b, acc[1][ct], 0, 0, 0);
        }
    }

    // D layout: col = lane&15, row = quad*4 + reg  (m89-verified)
    #pragma unroll
    for (int rt = 0; rt < 2; ++rt) {
        #pragma unroll
        for (int r = 0; r < 4; ++r) {
            int row = m0 + rt * 16 + quad * 4 + r;
            if (row < n) {
                if (OUTFP8) {
                    unsigned char* o = (unsigned char*)H + (size_t)row * 128 + l16;
                    #pragma unroll
                    for (int cp = 0; cp < 4; ++cp) {
                        int pk = __builtin_amdgcn_cvt_pk_fp8_f32(
                            acc[rt][2 * cp][r], acc[rt][2 * cp + 1][r], 0, false);
                        o[(2 * cp) * 16]     = (unsigned char)(pk & 0xFF);
                        o[(2 * cp + 1) * 16] = (unsigned char)((pk >> 8) & 0xFF);
                    }
                } else {
                    unsigned short* o = (unsigned short*)H + (size_t)row * 128 + l16;
                    #pragma unroll
                    for (int ct = 0; ct < 8; ++ct)
                        o[ct * 16] = f2bf(acc[rt][ct][r]);
                }
            }
        }
    }
}

// ---------------------------------------------------------------------------
// Init: zero packed[8N u64] (as uint4) + done counter; blocks [0,64) also
// transpose+convert W1/W2 to bf16 WT1/WT2.
// ---------------------------------------------------------------------------
__global__ __launch_bounds__(256) void k_init(u64* __restrict__ packed, int n4,
                                              int* __restrict__ done,
                                              const float* __restrict__ W1,
                                              const float* __restrict__ W2,
                                              unsigned short* __restrict__ WT1,
                                              unsigned short* __restrict__ WT2) {
    int idx = blockIdx.x * 256 + threadIdx.x;
    if (idx < n4) ((uint4*)packed)[idx] = make_uint4(0u, 0u, 0u, 0u);
    if (idx == 0) *done = 0;
    if (blockIdx.x < 64) {
        int j = blockIdx.x * 256 + threadIdx.x;  // 16384 total
        int k = j >> 7, nn = j & 127;
        WT1[nn * 128 + k] = f2bf(W1[k * 128 + nn]);
        WT2[nn * 128 + k] = f2bf(W2[k * 128 + nn]);
    }
}

// ---------------------------------------------------------------------------
// Fused gemm1 + hist: blocks [0,gGemm) compute h8 = fp8(x@W1) (MFMA pipe);
// blocks [gGemm, ...) do the 8-replica u64 histogram (atomic/TCC pipe).
// Replica r = (i>>8)&7, rank[i] = per-replica arrival order (atomic return).
// ---------------------------------------------------------------------------
__global__ __launch_bounds__(256) void k_gemm1_hist(const float* __restrict__ x,
                                                    const unsigned short* __restrict__ WT1,
                                                    unsigned char* __restrict__ h8,
                                                    const int* __restrict__ dst,
                                                    const float* __restrict__ ew,
                                                    u64* __restrict__ packed,
                                                    int* __restrict__ rank,
                                                    int E, int N, int gGemm) {
    const int b = blockIdx.x;
    if (b < gGemm) {
        gemm_body<1, 1>(x, WT1, h8, N, b);
        return;
    }
    int i = (b - gGemm) * 256 + threadIdx.x;
    if (i < E) {
        int d = dst[i];
        int r = (i >> 8) & 7;
        u64 add = (1ULL << 44) + (u64)(ew[i] * 4294967296.0f);
        u64 old = atomicAdd(&packed[(size_t)r * N + d], add);
        rank[i] = (int)(old >> 44);
    }
}

// ---------------------------------------------------------------------------
// Scan (one kernel): per-1024-chunk local exclusive scan of total counts into
// rowptr, fused decode (dinv, 8x8-bit replica bases), chunk totals release-
// stored into csums; last block (done counter) wave-scans the <=64 totals
// into exclusive chunk offsets in place.
// ---------------------------------------------------------------------------
__global__ __launch_bounds__(256) void k_scan(const u64* __restrict__ packed,
                                              float* __restrict__ dinv,
                                              u64* __restrict__ bases,
                                              int* __restrict__ rowptr,
                                              int* __restrict__ csums,
                                              int* __restrict__ done, int nNodes) {
    __shared__ int s[256];
    __shared__ int lastFlag;
    const int t = threadIdx.x;
    const int base = blockIdx.x * 1024 + t * 4;
    const int n = nNodes + 1;  // scan domain: N counts + trailing 0
    int v[4];
    #pragma unroll
    for (int u = 0; u < 4; ++u) {
        int idx = base + u;
        int c = 0;
        if (idx < nNodes) {
            const u64 mask = (1ULL << 44) - 1;
            u64 ssum = 0;
            u64 bs = 0;
            uint32 cum = 0;
            #pragma unroll
            for (int r = 0; r < 8; ++r) {
                u64 pv = packed[(size_t)r * nNodes + idx];
                bs |= (u64)cum << (8 * r);  // field 0 = 0
                cum += (uint32)(pv >> 44);
                ssum += (pv & mask);
            }
            c = (int)cum;
            float deg = 1.0f + (float)ssum * (1.0f / 4294967296.0f);
            dinv[idx] = rsqrtf(deg);
            bases[idx] = bs;
        }
        v[u] = c;
    }
    s[t] = v[0] + v[1] + v[2] + v[3];
    __syncthreads();
    #pragma unroll
    for (int off = 1; off < 256; off <<= 1) {
        int x = (t >= off) ? s[t - off] : 0;
        __syncthreads();
        s[t] += x;
        __syncthreads();
    }
    if (t == 255)
        __hip_atomic_store(&csums[blockIdx.x], s[255], __ATOMIC_RELEASE,
                           __HIP_MEMORY_SCOPE_AGENT);
    int e = (t == 0) ? 0 : s[t - 1];
    if (base + 0 < n) rowptr[base + 0] = e;
    if (base + 1 < n) rowptr[base + 1] = e + v[0];
    if (base + 2 < n) rowptr[base + 2] = e + v[0] + v[1];
    if (base + 3 < n) rowptr[base + 3] = e + v[0] + v[1] + v[2];

    // last-block: exclusive scan of the gridDim.x (<=64) chunk totals
    __syncthreads();  // all stores issued (incl. t255's release store)
    if (t == 0) {
        int prev = __hip_atomic_fetch_add(done, 1, __ATOMIC_ACQ_REL,
                                          __HIP_MEMORY_SCOPE_AGENT);
        lastFlag = (prev == (int)gridDim.x - 1);
    }
    __syncthreads();
    if (lastFlag && t < 64) {
        int g = (int)gridDim.x;
        int orig = (t < g) ? __hip_atomic_load(&csums[t], __ATOMIC_ACQUIRE,
                                               __HIP_MEMORY_SCOPE_AGENT)
                           : 0;
        int vv = orig;
        #pragma unroll
        for (int off = 1; off < 64; off <<= 1) {
            int y = __shfl_up(vv, off, 64);
            if (t >= off) vv += y;
        }
        if (t < g) csums[t] = vv - orig;  // exclusive chunk offset
    }
}

// Fill CSR (atomic-free):
//   pos = rowptr_local[d] + csums[d>>10] + base_replica(d, r) + rank[e].
__global__ __launch_bounds__(256) void k_fill(const int* __restrict__ src,
                                              const int* __restrict__ dst,
                                              const float* __restrict__ ew,
                                              const float* __restrict__ dinv,
                                              const int* __restrict__ rowptr,
                                              const int* __restrict__ csums,
                                              const u64* __restrict__ bases,
                                              const int* __restrict__ rank,
                                              float2* __restrict__ csr, int e) {
    int i = blockIdx.x * 256 + threadIdx.x;
    if (i < e) {
        int s = src[i], d = dst[i];
        int r = (i >> 8) & 7;  // must match k_gemm1_hist's replica map
        float nrm = dinv[s] * ew[i] * dinv[d];
        int pos = rowptr[d] + csums[d >> 10]
                + (int)((bases[d] >> (8 * r)) & 0xFF) + rank[i];
        csr[pos] = make_float2(__int_as_float(s), nrm);
    }
}

// ---------------------------------------------------------------------------
// CSR gather helper: 8-wide fp32 FMA from fp8 (uint2) rows.
// ---------------------------------------------------------------------------
__device__ __forceinline__ void fma8_f8(float* acc, uint2 u, float w) {
    f32x2 f;
    f = __builtin_amdgcn_cvt_pk_f32_fp8((int)u.x, false);
    acc[0] += f[0] * w; acc[1] += f[1] * w;
    f = __builtin_amdgcn_cvt_pk_f32_fp8((int)u.x, true);
    acc[2] += f[0] * w; acc[3] += f[1] * w;
    f = __builtin_amdgcn_cvt_pk_f32_fp8((int)u.y, false);
    acc[4] += f[0] * w; acc[5] += f[1] * w;
    f = __builtin_amdgcn_cvt_pk_f32_fp8((int)u.y, true);
    acc[6] += f[0] * w; acc[7] += f[1] * w;
}

// ---------------------------------------------------------------------------
// Layer-1 aggregation: g8 = fp8(relu(agg(h8) + b1)).
// One 64-lane wave per node (4 nodes/block), quarter-wave CSR layout: each
// 16-lane quarter reads full fp8 feature rows (uint2 = 8 fp8/lane, 128 B row),
// 16 edges in flight per iter. Partial sums combined via __shfl_xor(16/32).
// ---------------------------------------------------------------------------
__global__ __launch_bounds__(256) void k_ag1(const unsigned char* __restrict__ h8,
                                             const float2* __restrict__ csr,
                                             const int* __restrict__ rowptr,
                                             const int* __restrict__ csums,
                                             const float* __restrict__ dinv,
                                             const float4* __restrict__ bias4,
                                             unsigned char* __restrict__ g8, int N) {
    int node = blockIdx.x * 4 + (threadIdx.x >> 6);
    if (node >= N) return;
    const int lane = threadIdx.x & 63;
    const int q = lane >> 4, l = lane & 15;
    const int start = rowptr[node] + csums[node >> 10];
    const int end   = rowptr[node + 1] + csums[(node + 1) >> 10];
    const uint2* H2 = (const uint2*)h8;

    // self-loop (ew=1, norm=dinv^2): counted once, via quarter 0 only
    float di = dinv[node];
    float selfw = (q == 0) ? di * di : 0.0f;
    float acc[8] = {};
    fma8_f8(acc, H2[(size_t)node * 16 + l], selfw);

    for (int k = start; k < end; k += 16) {  // 16 edges/iter across quarters
        float2 c[4];
        float w[4];
        #pragma unroll
        for (int j = 0; j < 4; ++j) {
            int ej = k + q + 4 * j;
            c[j] = csr[ej < end ? ej : end - 1];
            w[j] = (ej < end) ? c[j].y : 0.0f;
        }
        uint2 u[4];
        #pragma unroll
        for (int j = 0; j < 4; ++j)
            u[j] = H2[(size_t)__float_as_int(c[j].x) * 16 + l];
        #pragma unroll
        for (int j = 0; j < 4; ++j) fma8_f8(acc, u[j], w[j]);
    }

    #pragma unroll
    for (int j = 0; j < 8; ++j) {
        acc[j] += __shfl_xor(acc[j], 16, 64);
        acc[j] += __shfl_xor(acc[j], 32, 64);
    }

    if (q == 0) {  // lanes 0..15 write the fp8 row (cols l*8..l*8+7)
        float4 b0 = bias4[l * 2], b1v = bias4[l * 2 + 1];
        acc[0] += b0.x;  acc[1] += b0.y;  acc[2] += b0.z;  acc[3] += b0.w;
        acc[4] += b1v.x; acc[5] += b1v.y; acc[6] += b1v.z; acc[7] += b1v.w;
        #pragma unroll
        for (int j = 0; j < 8; ++j) acc[j] = fmaxf(acc[j], 0.0f);
        uint2 o;
        int w0 = __builtin_amdgcn_cvt_pk_fp8_f32(acc[0], acc[1], 0, false);
        w0     = __builtin_amdgcn_cvt_pk_fp8_f32(acc[2], acc[3], w0, true);
        int w1 = __builtin_amdgcn_cvt_pk_fp8_f32(acc[4], acc[5], 0, false);
        w1     = __builtin_amdgcn_cvt_pk_fp8_f32(acc[6], acc[7], w1, true);
        o.x = (uint32)w0; o.y = (uint32)w1;
        ((uint2*)g8)[(size_t)node * 16 + l] = o;
    }
}

// ---------------------------------------------------------------------------
// Layer-2 fused aggregate + GEMM + sigmoid (agg is linear: agg(g)@W2 ==
// agg(g@W2)). Block = 256 threads (4 waves) = 16 nodes. Phase 1: wave wv
// gathers nodes [nb+wv*4, nb+wv*4+4) over the fp8 g8 table (no bias/relu),
// writes fp32 sums as bf16 rows into LDS sA[16][136] (pad 8 -> 2-way bank
// conflict = free). Phase 2: each wave computes the 16x32 col-slice of
// sA @ W2 at cols [wv*32,wv*32+32), adds b2, sigmoid, writes fp32 out.
// ---------------------------------------------------------------------------
__global__ __launch_bounds__(256) void k_ag2s(const unsigned char* __restrict__ g8,
                                              const float2* __restrict__ csr,
                                              const int* __restrict__ rowptr,
                                              const int* __restrict__ csums,
                                              const float* __restrict__ dinv,
                                              const float* __restrict__ b2,
                                              const unsigned short* __restrict__ WT2,
                                              float* __restrict__ out, int N) {
    __shared__ unsigned short sA[16][136];
    const int lane = threadIdx.x & 63;
    const int wv   = threadIdx.x >> 6;
    const int q    = lane >> 4;     // quarter (== MFMA quad later)
    const int l    = lane & 15;
    const int nb   = blockIdx.x * 16;
    const uint2* G2 = (const uint2*)g8;

    // ---- phase 1: gather 4 nodes per wave into LDS (no bias, no act) ----
    for (int j = 0; j < 4; ++j) {
        const int node = nb + wv * 4 + j;
        float acc[8] = {};
        if (node < N) {   // wave-uniform branch
            const int start = rowptr[node] + csums[node >> 10];
            const int end   = rowptr[node + 1] + csums[(node + 1) >> 10];
            float di = dinv[node];
            float selfw = (q == 0) ? di * di : 0.0f;  // self-loop once (q0)
            fma8_f8(acc, G2[(size_t)node * 16 + l], selfw);

            for (int k = start; k < end; k += 16) {  // 16 edges/iter
                float2 c[4];
                float w[4];
                #pragma unroll
                for (int jj = 0; jj < 4; ++jj) {
                    int ej = k + q + 4 * jj;
                    c[jj] = csr[ej < end ? ej : end - 1];
                    w[jj] = (ej < end) ? c[jj].y : 0.0f;
                }
                uint2 u[4];
                #pragma unroll
                for (int jj = 0; jj < 4; ++jj)
                    u[jj] = G2[(size_t)__float_as_int(c[jj].x) * 16 + l];
                #pragma unroll
                for (int jj = 0; jj < 4; ++jj) fma8_f8(acc, u[jj], w[jj]);
            }
            // combine quarters
            #pragma unroll
            for (int t = 0; t < 8; ++t) {
                acc[t] += __shfl_xor(acc[t], 16, 64);
                acc[t] += __shfl_xor(acc[t], 32, 64);
            }
        }
        if (q == 0) {  // lanes 0..15 write the bf16 row (zeros if node >= N)
            uint4 o = make_uint4(0u, 0u, 0u, 0u);
            if (node < N) {
                o.x = (uint32)f2bf(acc[0]) | ((uint32)f2bf(acc[1]) << 16);
                o.y = (uint32)f2bf(acc[2]) | ((uint32)f2bf(acc[3]) << 16);
                o.z = (uint32)f2bf(acc[4]) | ((uint32)f2bf(acc[5]) << 16);
                o.w = (uint32)f2bf(acc[6]) | ((uint32)f2bf(acc[7]) << 16);
            }
            *(uint4*)&sA[wv * 4 + j][l * 8] = o;
        }
    }

    __syncthreads();

    // ---- phase 2: out[nb..nb+16) = sigmoid(sA @ W2 + b2), cols [wv*32,+32) ----
    f32x4 a2[2] = {};
    #pragma unroll
    for (int ks = 0; ks < 4; ++ks) {
        const int k0 = ks * 32 + q * 8;
        bf16x8 a = *(const bf16x8*)&sA[l][k0];
        #pragma unroll
        for (int ct = 0; ct < 2; ++ct) {
            bf16x8 b = *(const bf16x8*)(WT2 + (size_t)(wv * 32 + ct * 16 + l) * 128 + k0);
            a2[ct] = __builtin_amdgcn_mfma_f32_16x16x32_bf16(a, b, a2[ct], 0, 0, 0);
        }
    }
    // D layout: col (within 16-tile) = lane&15, row = q*4 + reg
    #pragma unroll
    for (int ct = 0; ct < 2; ++ct) {
        const int col = wv * 32 + ct * 16 + l;
        const float bb = b2[col];
        #pragma unroll
        for (int r = 0; r < 4; ++r) {
            int row = nb + q * 4 + r;
            if (row < N) {
                float v = a2[ct][r] + bb;
                out[(size_t)row * 128 + col] = 1.0f / (1.0f + expf(-v));
            }
        }
    }
}

extern "C" void kernel_launch(void* const* d_in, const int* in_sizes, int n_in,
                              void* d_out, int out_size, void* d_ws, size_t ws_size,
                              hipStream_t stream) {
    const float* x  = (const float*)d_in[0];
    const int*   ei = (const int*)d_in[1];
    const float* ew = (const float*)d_in[2];
    const float* W1 = (const float*)d_in[3];
    const float* b1 = (const float*)d_in[4];
    const float* W2 = (const float*)d_in[5];
    const float* b2 = (const float*)d_in[6];

    const int N = in_sizes[0] / 128;
    const int E = in_sizes[2];
    const int* src = ei;
    const int* dst = ei + E;
    float* out = (float*)d_out;

    // Workspace layout (256B-aligned slabs):
    //   dinv [N] | rowptr [N+1] | csums [1024] | done | bases [N u64]
    //   | WT1 | WT2 | rank [E] | csr [E f2] | h8 [N*128 fp8]
    //   | g8 [N*128 fp8]
    //   (packed u64[8N] aliases g8: dead after k_scan, g8 written at k_ag1;
    //    8N u64 = 3.2 MB < 6.4 MB g8 slab)
    auto align = [](size_t v) { return (v + 255) & ~(size_t)255; };
    char* p = (char*)d_ws;
    float*  dinv   = (float*)p;   p += align((size_t)N * 4);
    int*    rowptr = (int*)p;     p += align((size_t)(N + 1) * 4);
    int*    csums  = (int*)p;     p += align((size_t)1024 * 4);
    int*    done   = (int*)p;     p += align((size_t)256);
    u64*    bases  = (u64*)p;     p += align((size_t)N * 8);
    unsigned short* WT1 = (unsigned short*)p; p += align((size_t)128 * 128 * 2);
    unsigned short* WT2 = (unsigned short*)p; p += align((size_t)128 * 128 * 2);
    int*    rank   = (int*)p;     p += align((size_t)E * 4);
    float2* csr    = (float2*)p;  p += align((size_t)E * 8);
    unsigned char*  h8 = (unsigned char*)p;  p += align((size_t)N * 128);
    unsigned char*  g8 = (unsigned char*)p;
    u64* packed = (u64*)g8;  // alias (dead after scan; g8 written at ag1)

    const int nbE = (E + 255) / 256;
    const int gScan = (N + 1 + 1023) / 1024;   // 49 for N=50000 (<=64 required)
    const int gGemm = (N + 127) / 128;
    const int gAg1  = (N + 3) / 4;
    const int gAg2  = (N + 15) / 16;
    const int n4 = N * 4;                      // 8N u64 = 4N uint4
    const int gInit = ((n4 + 255) / 256) < 64 ? 64 : ((n4 + 255) / 256);

    // --- Build (+ layer-1 GEMM overlapped with hist) ---
    k_init<<<gInit, 256, 0, stream>>>(packed, n4, done, W1, W2, WT1, WT2);
    k_gemm1_hist<<<gGemm + nbE, 256, 0, stream>>>(x, WT1, h8, dst, ew, packed,
                                                  rank, E, N, gGemm);
    k_scan<<<gScan, 256, 0, stream>>>(packed, dinv, bases, rowptr, csums, done, N);
    k_fill<<<nbE, 256, 0, stream>>>(src, dst, ew, dinv, rowptr, csums, bases,
                                    rank, csr, E);

    // --- Layer 1: g8 = fp8(relu(agg(h8) + b1)) ---
    k_ag1<<<gAg1, 256, 0, stream>>>(h8, csr, rowptr, csums, dinv,
                                    (const float4*)b1, g8, N);

    // --- Layer 2 fused: out = sigmoid(agg(g8) @ W2 + b2) ---
    k_ag2s<<<gAg2, 256, 0, stream>>>(g8, csr, rowptr, csums, dinv, b2,
                                     WT2, out, N);
}

// Round 5
// 190.167 us; speedup vs baseline: 1.1266x; 1.0594x over previous
//
#include <hip/hip_runtime.h>
#include <math.h>

// ---------------------------------------------------------------------------
// GCN 2-layer forward on MI355X.
// Round 16 (resubmit; R16 bench was an infra failure, no counters returned).
// Gather kernels restructured node-per-quarter. Each 16-lane quarter owns ONE
// node (4 parallel nodes/wave, 16/block) and walks its edge list 8 edges per
// iteration (8 csr + 8 row loads in flight per quarter). Removes the serial
// 4-node-per-wave chain, parallelizes node setup, deletes the cross-quarter
// __shfl_xor reduction and q0-only writes.
// Everything else (pipeline, fp8 tables, agg-then-GEMM layer 2) = R15.
// ---------------------------------------------------------------------------

typedef unsigned int uint32;
typedef unsigned long long u64;
typedef __attribute__((ext_vector_type(8))) short bf16x8;   // 8 bf16 (4 VGPRs)
typedef __attribute__((ext_vector_type(4))) float f32x4;
typedef __attribute__((ext_vector_type(2))) float f32x2;

__device__ __forceinline__ unsigned short f2bf(float f) {   // RNE fp32->bf16
    uint32 b = __float_as_uint(f);
    return (unsigned short)((b + 0x7FFFu + ((b >> 16) & 1u)) >> 16);
}

// ---------------------------------------------------------------------------
// MFMA GEMM body: H[n x 128] = A[n x 128] @ W (WT bf16 transposed).
// 256 threads = 4 waves; each wave 32 rows x 128 cols (2x8 16x16 tiles),
// K=128 in 4 steps. AFP32: A fp32 (converted inline) vs bf16.
// OUTFP8: D written as fp8 e4m3 bytes vs bf16.
// ---------------------------------------------------------------------------
template <int AFP32, int OUTFP8>
__device__ __forceinline__ void gemm_body(const void* __restrict__ Ap,
                                          const unsigned short* __restrict__ WT,
                                          void* __restrict__ H,
                                          int n, int tb) {
    const int lane = threadIdx.x & 63;
    const int wv   = threadIdx.x >> 6;
    const int quad = lane >> 4;
    const int l16  = lane & 15;
    const int m0   = tb * 128 + wv * 32;
    f32x4 acc[2][8] = {};

    #pragma unroll
    for (int ks = 0; ks < 4; ++ks) {
        const int k0 = ks * 32 + quad * 8;
        bf16x8 a[2];
        #pragma unroll
        for (int rt = 0; rt < 2; ++rt) {
            int row = m0 + rt * 16 + l16;
            if (row >= n) row = n - 1;  // clamp; stores are guarded
            if (AFP32) {
                const float* Af = (const float*)Ap + (size_t)row * 128 + k0;
                float4 f0 = *(const float4*)(Af);
                float4 f1 = *(const float4*)(Af + 4);
                bf16x8 v;
                v[0] = (short)f2bf(f0.x); v[1] = (short)f2bf(f0.y);
                v[2] = (short)f2bf(f0.z); v[3] = (short)f2bf(f0.w);
                v[4] = (short)f2bf(f1.x); v[5] = (short)f2bf(f1.y);
                v[6] = (short)f2bf(f1.z); v[7] = (short)f2bf(f1.w);
                a[rt] = v;
            } else {
                const unsigned short* Ab = (const unsigned short*)Ap + (size_t)row * 128 + k0;
                a[rt] = *(const bf16x8*)Ab;
            }
        }
        #pragma unroll
        for (int ct = 0; ct < 8; ++ct) {
            bf16x8 b = *(const bf16x8*)(WT + (size_t)(ct * 16 + l16) * 128 + k0);
            acc[0][ct] = __builtin_amdgcn_mfma_f32_16x16x32_bf16(a[0], b, acc[0][ct], 0, 0, 0);
            acc[1][ct] = __builtin_amdgcn_mfma_f32_16x16x32_bf16(a[1], b, acc[1][ct], 0, 0, 0);
        }
    }

    // D layout: col = lane&15, row = quad*4 + reg  (m89-verified)
    #pragma unroll
    for (int rt = 0; rt < 2; ++rt) {
        #pragma unroll
        for (int r = 0; r < 4; ++r) {
            int row = m0 + rt * 16 + quad * 4 + r;
            if (row < n) {
                if (OUTFP8) {
                    unsigned char* o = (unsigned char*)H + (size_t)row * 128 + l16;
                    #pragma unroll
                    for (int cp = 0; cp < 4; ++cp) {
                        int pk = __builtin_amdgcn_cvt_pk_fp8_f32(
                            acc[rt][2 * cp][r], acc[rt][2 * cp + 1][r], 0, false);
                        o[(2 * cp) * 16]     = (unsigned char)(pk & 0xFF);
                        o[(2 * cp + 1) * 16] = (unsigned char)((pk >> 8) & 0xFF);
                    }
                } else {
                    unsigned short* o = (unsigned short*)H + (size_t)row * 128 + l16;
                    #pragma unroll
                    for (int ct = 0; ct < 8; ++ct)
                        o[ct * 16] = f2bf(acc[rt][ct][r]);
                }
            }
        }
    }
}

// ---------------------------------------------------------------------------
// Init: zero packed[8N u64] (as uint4) + done counter; blocks [0,64) also
// transpose+convert W1/W2 to bf16 WT1/WT2.
// ---------------------------------------------------------------------------
__global__ __launch_bounds__(256) void k_init(u64* __restrict__ packed, int n4,
                                              int* __restrict__ done,
                                              const float* __restrict__ W1,
                                              const float* __restrict__ W2,
                                              unsigned short* __restrict__ WT1,
                                              unsigned short* __restrict__ WT2) {
    int idx = blockIdx.x * 256 + threadIdx.x;
    if (idx < n4) ((uint4*)packed)[idx] = make_uint4(0u, 0u, 0u, 0u);
    if (idx == 0) *done = 0;
    if (blockIdx.x < 64) {
        int j = blockIdx.x * 256 + threadIdx.x;  // 16384 total
        int k = j >> 7, nn = j & 127;
        WT1[nn * 128 + k] = f2bf(W1[k * 128 + nn]);
        WT2[nn * 128 + k] = f2bf(W2[k * 128 + nn]);
    }
}

// ---------------------------------------------------------------------------
// Fused gemm1 + hist: blocks [0,gGemm) compute h8 = fp8(x@W1) (MFMA pipe);
// blocks [gGemm, ...) do the 8-replica u64 histogram (atomic/TCC pipe).
// Replica r = (i>>8)&7, rank[i] = per-replica arrival order (atomic return).
// ---------------------------------------------------------------------------
__global__ __launch_bounds__(256) void k_gemm1_hist(const float* __restrict__ x,
                                                    const unsigned short* __restrict__ WT1,
                                                    unsigned char* __restrict__ h8,
                                                    const int* __restrict__ dst,
                                                    const float* __restrict__ ew,
                                                    u64* __restrict__ packed,
                                                    int* __restrict__ rank,
                                                    int E, int N, int gGemm) {
    const int b = blockIdx.x;
    if (b < gGemm) {
        gemm_body<1, 1>(x, WT1, h8, N, b);
        return;
    }
    int i = (b - gGemm) * 256 + threadIdx.x;
    if (i < E) {
        int d = dst[i];
        int r = (i >> 8) & 7;
        u64 add = (1ULL << 44) + (u64)(ew[i] * 4294967296.0f);
        u64 old = atomicAdd(&packed[(size_t)r * N + d], add);
        rank[i] = (int)(old >> 44);
    }
}

// ---------------------------------------------------------------------------
// Scan (one kernel): per-1024-chunk local exclusive scan of total counts into
// rowptr, fused decode (dinv, 8x8-bit replica bases), chunk totals release-
// stored into csums; last block (done counter) wave-scans the <=64 totals
// into exclusive chunk offsets in place.
// ---------------------------------------------------------------------------
__global__ __launch_bounds__(256) void k_scan(const u64* __restrict__ packed,
                                              float* __restrict__ dinv,
                                              u64* __restrict__ bases,
                                              int* __restrict__ rowptr,
                                              int* __restrict__ csums,
                                              int* __restrict__ done, int nNodes) {
    __shared__ int s[256];
    __shared__ int lastFlag;
    const int t = threadIdx.x;
    const int base = blockIdx.x * 1024 + t * 4;
    const int n = nNodes + 1;  // scan domain: N counts + trailing 0
    int v[4];
    #pragma unroll
    for (int u = 0; u < 4; ++u) {
        int idx = base + u;
        int c = 0;
        if (idx < nNodes) {
            const u64 mask = (1ULL << 44) - 1;
            u64 ssum = 0;
            u64 bs = 0;
            uint32 cum = 0;
            #pragma unroll
            for (int r = 0; r < 8; ++r) {
                u64 pv = packed[(size_t)r * nNodes + idx];
                bs |= (u64)cum << (8 * r);  // field 0 = 0
                cum += (uint32)(pv >> 44);
                ssum += (pv & mask);
            }
            c = (int)cum;
            float deg = 1.0f + (float)ssum * (1.0f / 4294967296.0f);
            dinv[idx] = rsqrtf(deg);
            bases[idx] = bs;
        }
        v[u] = c;
    }
    s[t] = v[0] + v[1] + v[2] + v[3];
    __syncthreads();
    #pragma unroll
    for (int off = 1; off < 256; off <<= 1) {
        int x = (t >= off) ? s[t - off] : 0;
        __syncthreads();
        s[t] += x;
        __syncthreads();
    }
    if (t == 255)
        __hip_atomic_store(&csums[blockIdx.x], s[255], __ATOMIC_RELEASE,
                           __HIP_MEMORY_SCOPE_AGENT);
    int e = (t == 0) ? 0 : s[t - 1];
    if (base + 0 < n) rowptr[base + 0] = e;
    if (base + 1 < n) rowptr[base + 1] = e + v[0];
    if (base + 2 < n) rowptr[base + 2] = e + v[0] + v[1];
    if (base + 3 < n) rowptr[base + 3] = e + v[0] + v[1] + v[2];

    // last-block: exclusive scan of the gridDim.x (<=64) chunk totals
    __syncthreads();  // all stores issued (incl. t255's release store)
    if (t == 0) {
        int prev = __hip_atomic_fetch_add(done, 1, __ATOMIC_ACQ_REL,
                                          __HIP_MEMORY_SCOPE_AGENT);
        lastFlag = (prev == (int)gridDim.x - 1);
    }
    __syncthreads();
    if (lastFlag && t < 64) {
        int g = (int)gridDim.x;
        int orig = (t < g) ? __hip_atomic_load(&csums[t], __ATOMIC_ACQUIRE,
                                               __HIP_MEMORY_SCOPE_AGENT)
                           : 0;
        int vv = orig;
        #pragma unroll
        for (int off = 1; off < 64; off <<= 1) {
            int y = __shfl_up(vv, off, 64);
            if (t >= off) vv += y;
        }
        if (t < g) csums[t] = vv - orig;  // exclusive chunk offset
    }
}

// Fill CSR (atomic-free):
//   pos = rowptr_local[d] + csums[d>>10] + base_replica(d, r) + rank[e].
__global__ __launch_bounds__(256) void k_fill(const int* __restrict__ src,
                                              const int* __restrict__ dst,
                                              const float* __restrict__ ew,
                                              const float* __restrict__ dinv,
                                              const int* __restrict__ rowptr,
                                              const int* __restrict__ csums,
                                              const u64* __restrict__ bases,
                                              const int* __restrict__ rank,
                                              float2* __restrict__ csr, int e) {
    int i = blockIdx.x * 256 + threadIdx.x;
    if (i < e) {
        int s = src[i], d = dst[i];
        int r = (i >> 8) & 7;  // must match k_gemm1_hist's replica map
        float nrm = dinv[s] * ew[i] * dinv[d];
        int pos = rowptr[d] + csums[d >> 10]
                + (int)((bases[d] >> (8 * r)) & 0xFF) + rank[i];
        csr[pos] = make_float2(__int_as_float(s), nrm);
    }
}

// ---------------------------------------------------------------------------
// CSR gather helper: 8-wide fp32 FMA from fp8 (uint2) rows.
// ---------------------------------------------------------------------------
__device__ __forceinline__ void fma8_f8(float* acc, uint2 u, float w) {
    f32x2 f;
    f = __builtin_amdgcn_cvt_pk_f32_fp8((int)u.x, false);
    acc[0] += f[0] * w; acc[1] += f[1] * w;
    f = __builtin_amdgcn_cvt_pk_f32_fp8((int)u.x, true);
    acc[2] += f[0] * w; acc[3] += f[1] * w;
    f = __builtin_amdgcn_cvt_pk_f32_fp8((int)u.y, false);
    acc[4] += f[0] * w; acc[5] += f[1] * w;
    f = __builtin_amdgcn_cvt_pk_f32_fp8((int)u.y, true);
    acc[6] += f[0] * w; acc[7] += f[1] * w;
}

// ---------------------------------------------------------------------------
// Per-quarter CSR edge walk: the 16 lanes of one quarter own one node and
// process 8 edges per iteration (8 broadcast csr loads + 8 random 128 B row
// loads in flight). acc accumulates cols [l*8, l*8+8) in fp32.
// ---------------------------------------------------------------------------
__device__ __forceinline__ void gather_q8(float* acc, const uint2* __restrict__ T,
                                          const float2* __restrict__ csr,
                                          int start, int end, int l) {
    for (int k = start; k < end; k += 8) {
        float2 c[8];
        float w[8];
        uint2 u[8];
        #pragma unroll
        for (int j = 0; j < 8; ++j) {
            int ej = k + j;
            c[j] = csr[ej < end ? ej : end - 1];
            w[j] = (ej < end) ? c[j].y : 0.0f;
        }
        #pragma unroll
        for (int j = 0; j < 8; ++j)
            u[j] = T[(size_t)__float_as_int(c[j].x) * 16 + l];
        #pragma unroll
        for (int j = 0; j < 8; ++j) fma8_f8(acc, u[j], w[j]);
    }
}

// ---------------------------------------------------------------------------
// Layer-1 aggregation: g8 = fp8(relu(agg(h8) + b1)).
// Node-per-quarter: 16 nodes/block (4 waves x 4 quarters). Each quarter reads
// full fp8 rows (uint2 = 8 fp8/lane, 128 B row); no cross-lane reduction;
// all 64 lanes write (uint2 per lane, 4 node-rows per wave).
// ---------------------------------------------------------------------------
__global__ __launch_bounds__(256) void k_ag1(const unsigned char* __restrict__ h8,
                                             const float2* __restrict__ csr,
                                             const int* __restrict__ rowptr,
                                             const int* __restrict__ csums,
                                             const float* __restrict__ dinv,
                                             const float4* __restrict__ bias4,
                                             unsigned char* __restrict__ g8, int N) {
    const int lane = threadIdx.x & 63;
    const int q = lane >> 4, l = lane & 15;
    const int node = blockIdx.x * 16 + (threadIdx.x >> 6) * 4 + q;
    if (node >= N) return;   // lane-divergent ok: no barriers below
    const uint2* H2 = (const uint2*)h8;
    const int start = rowptr[node] + csums[node >> 10];
    const int end   = rowptr[node + 1] + csums[(node + 1) >> 10];
    const float di = dinv[node];

    float acc[8] = {};
    fma8_f8(acc, H2[(size_t)node * 16 + l], di * di);   // self-loop
    gather_q8(acc, H2, csr, start, end, l);

    float4 b0 = bias4[l * 2], b1v = bias4[l * 2 + 1];
    acc[0] += b0.x;  acc[1] += b0.y;  acc[2] += b0.z;  acc[3] += b0.w;
    acc[4] += b1v.x; acc[5] += b1v.y; acc[6] += b1v.z; acc[7] += b1v.w;
    #pragma unroll
    for (int j = 0; j < 8; ++j) acc[j] = fmaxf(acc[j], 0.0f);
    uint2 o;
    int w0 = __builtin_amdgcn_cvt_pk_fp8_f32(acc[0], acc[1], 0, false);
    w0     = __builtin_amdgcn_cvt_pk_fp8_f32(acc[2], acc[3], w0, true);
    int w1 = __builtin_amdgcn_cvt_pk_fp8_f32(acc[4], acc[5], 0, false);
    w1     = __builtin_amdgcn_cvt_pk_fp8_f32(acc[6], acc[7], w1, true);
    o.x = (uint32)w0; o.y = (uint32)w1;
    ((uint2*)g8)[(size_t)node * 16 + l] = o;
}

// ---------------------------------------------------------------------------
// Layer-2 fused aggregate + GEMM + sigmoid (agg is linear: agg(g)@W2 ==
// agg(g@W2)). Block = 256 threads (4 waves) = 16 nodes, node-per-quarter.
// Phase 1: each quarter gathers its node over the fp8 g8 table (no bias/act),
// all lanes write bf16 rows into LDS sA[16][136] (pad 8 -> 2-way bank
// conflict = free). Phase 2: each wave computes the 16x32 col-slice of
// sA @ W2 at cols [wv*32,wv*32+32), adds b2, sigmoid, writes fp32 out.
// ---------------------------------------------------------------------------
__global__ __launch_bounds__(256) void k_ag2s(const unsigned char* __restrict__ g8,
                                              const float2* __restrict__ csr,
                                              const int* __restrict__ rowptr,
                                              const int* __restrict__ csums,
                                              const float* __restrict__ dinv,
                                              const float* __restrict__ b2,
                                              const unsigned short* __restrict__ WT2,
                                              float* __restrict__ out, int N) {
    __shared__ unsigned short sA[16][136];
    const int lane = threadIdx.x & 63;
    const int wv   = threadIdx.x >> 6;
    const int q    = lane >> 4;     // quarter (== MFMA quad later)
    const int l    = lane & 15;
    const int nb   = blockIdx.x * 16;
    const int node = nb + wv * 4 + q;
    const uint2* G2 = (const uint2*)g8;

    // ---- phase 1: each quarter gathers its node (no bias, no act) ----
    float acc[8] = {};
    if (node < N) {
        const int start = rowptr[node] + csums[node >> 10];
        const int end   = rowptr[node + 1] + csums[(node + 1) >> 10];
        const float di = dinv[node];
        fma8_f8(acc, G2[(size_t)node * 16 + l], di * di);   // self-loop
        gather_q8(acc, G2, csr, start, end, l);
    }
    uint4 o = make_uint4(0u, 0u, 0u, 0u);   // zero rows for node >= N
    if (node < N) {
        o.x = (uint32)f2bf(acc[0]) | ((uint32)f2bf(acc[1]) << 16);
        o.y = (uint32)f2bf(acc[2]) | ((uint32)f2bf(acc[3]) << 16);
        o.z = (uint32)f2bf(acc[4]) | ((uint32)f2bf(acc[5]) << 16);
        o.w = (uint32)f2bf(acc[6]) | ((uint32)f2bf(acc[7]) << 16);
    }
    *(uint4*)&sA[wv * 4 + q][l * 8] = o;

    __syncthreads();

    // ---- phase 2: out[nb..nb+16) = sigmoid(sA @ W2 + b2), cols [wv*32,+32) ----
    f32x4 a2[2] = {};
    #pragma unroll
    for (int ks = 0; ks < 4; ++ks) {
        const int k0 = ks * 32 + q * 8;
        bf16x8 a = *(const bf16x8*)&sA[l][k0];
        #pragma unroll
        for (int ct = 0; ct < 2; ++ct) {
            bf16x8 b = *(const bf16x8*)(WT2 + (size_t)(wv * 32 + ct * 16 + l) * 128 + k0);
            a2[ct] = __builtin_amdgcn_mfma_f32_16x16x32_bf16(a, b, a2[ct], 0, 0, 0);
        }
    }
    // D layout: col (within 16-tile) = lane&15, row = q*4 + reg
    #pragma unroll
    for (int ct = 0; ct < 2; ++ct) {
        const int col = wv * 32 + ct * 16 + l;
        const float bb = b2[col];
        #pragma unroll
        for (int r = 0; r < 4; ++r) {
            int row = nb + q * 4 + r;
            if (row < N) {
                float v = a2[ct][r] + bb;
                out[(size_t)row * 128 + col] = 1.0f / (1.0f + expf(-v));
            }
        }
    }
}

extern "C" void kernel_launch(void* const* d_in, const int* in_sizes, int n_in,
                              void* d_out, int out_size, void* d_ws, size_t ws_size,
                              hipStream_t stream) {
    const float* x  = (const float*)d_in[0];
    const int*   ei = (const int*)d_in[1];
    const float* ew = (const float*)d_in[2];
    const float* W1 = (const float*)d_in[3];
    const float* b1 = (const float*)d_in[4];
    const float* W2 = (const float*)d_in[5];
    const float* b2 = (const float*)d_in[6];

    const int N = in_sizes[0] / 128;
    const int E = in_sizes[2];
    const int* src = ei;
    const int* dst = ei + E;
    float* out = (float*)d_out;

    // Workspace layout (256B-aligned slabs):
    //   dinv [N] | rowptr [N+1] | csums [1024] | done | bases [N u64]
    //   | WT1 | WT2 | rank [E] | csr [E f2] | h8 [N*128 fp8]
    //   | g8 [N*128 fp8]
    //   (packed u64[8N] aliases g8: dead after k_scan, g8 written at k_ag1;
    //    8N u64 = 3.2 MB < 6.4 MB g8 slab)
    auto align = [](size_t v) { return (v + 255) & ~(size_t)255; };
    char* p = (char*)d_ws;
    float*  dinv   = (float*)p;   p += align((size_t)N * 4);
    int*    rowptr = (int*)p;     p += align((size_t)(N + 1) * 4);
    int*    csums  = (int*)p;     p += align((size_t)1024 * 4);
    int*    done   = (int*)p;     p += align((size_t)256);
    u64*    bases  = (u64*)p;     p += align((size_t)N * 8);
    unsigned short* WT1 = (unsigned short*)p; p += align((size_t)128 * 128 * 2);
    unsigned short* WT2 = (unsigned short*)p; p += align((size_t)128 * 128 * 2);
    int*    rank   = (int*)p;     p += align((size_t)E * 4);
    float2* csr    = (float2*)p;  p += align((size_t)E * 8);
    unsigned char*  h8 = (unsigned char*)p;  p += align((size_t)N * 128);
    unsigned char*  g8 = (unsigned char*)p;
    u64* packed = (u64*)g8;  // alias (dead after scan; g8 written at ag1)

    const int nbE = (E + 255) / 256;
    const int gScan = (N + 1 + 1023) / 1024;   // 49 for N=50000 (<=64 required)
    const int gGemm = (N + 127) / 128;
    const int gAg1  = (N + 15) / 16;
    const int gAg2  = (N + 15) / 16;
    const int n4 = N * 4;                      // 8N u64 = 4N uint4
    const int gInit = ((n4 + 255) / 256) < 64 ? 64 : ((n4 + 255) / 256);

    // --- Build (+ layer-1 GEMM overlapped with hist) ---
    k_init<<<gInit, 256, 0, stream>>>(packed, n4, done, W1, W2, WT1, WT2);
    k_gemm1_hist<<<gGemm + nbE, 256, 0, stream>>>(x, WT1, h8, dst, ew, packed,
                                                  rank, E, N, gGemm);
    k_scan<<<gScan, 256, 0, stream>>>(packed, dinv, bases, rowptr, csums, done, N);
    k_fill<<<nbE, 256, 0, stream>>>(src, dst, ew, dinv, rowptr, csums, bases,
                                    rank, csr, E);

    // --- Layer 1: g8 = fp8(relu(agg(h8) + b1)) ---
    k_ag1<<<gAg1, 256, 0, stream>>>(h8, csr, rowptr, csums, dinv,
                                    (const float4*)b1, g8, N);

    // --- Layer 2 fused: out = sigmoid(agg(g8) @ W2 + b2) ---
    k_ag2s<<<gAg2, 256, 0, stream>>>(g8, csr, rowptr, csums, dinv, b2,
                                     WT2, out, N);
}